// Round 1
// baseline (2066.637 us; speedup 1.0000x reference)
//
#include <hip/hip_runtime.h>
#include <math.h>

// Problem constants
constexpr int B_  = 2;
constexpr int S_  = 2048;
constexpr int C_  = 1024;
constexpr int NH  = 16;
constexpr int DH  = 64;
constexpr int HD  = 1024;   // NH*DH
constexpr int M_  = B_ * S_;  // 4096
constexpr float SCALE = 0.125f; // 1/sqrt(64)

// ---------------------------------------------------------------------------
// Generic f32 GEMM body: C = A @ Bmat. A[M,K], Bmat[K,N], C[M,N], row-major.
// BM=BN=128, BK=16, 256 threads, 8x8 microtile. M%128==0, N%128==0, K%16==0.
// ---------------------------------------------------------------------------
__device__ __forceinline__ void gemm_body(const float* __restrict__ A,
                                          const float* __restrict__ Bmat,
                                          float* __restrict__ Cmat,
                                          int M, int N, int K,
                                          int m0, int n0)
{
    __shared__ float As[16][132];  // [k][m], padded
    __shared__ float Bs[16][132];  // [k][n], padded

    const int tid = threadIdx.x;
    const int tx = tid & 15;   // col group: cols tx*8 .. tx*8+7
    const int ty = tid >> 4;   // row group: rows ty*8 .. ty*8+7

    const int arow = tid >> 1;        // 0..127
    const int akg  = (tid & 1) * 8;   // 0 or 8
    const int brow = tid >> 4;        // 0..15
    const int bcg  = (tid & 15) * 8;  // 0..120

    float acc[8][8];
#pragma unroll
    for (int i = 0; i < 8; ++i)
#pragma unroll
        for (int j = 0; j < 8; ++j) acc[i][j] = 0.f;

    for (int k0 = 0; k0 < K; k0 += 16) {
        __syncthreads();  // protect LDS from previous iteration's readers
        // Load A tile (128 x 16), store transposed As[k][m]
        {
            const float4 a0 = *(const float4*)&A[(size_t)(m0 + arow) * K + k0 + akg];
            const float4 a1 = *(const float4*)&A[(size_t)(m0 + arow) * K + k0 + akg + 4];
            As[akg + 0][arow] = a0.x; As[akg + 1][arow] = a0.y;
            As[akg + 2][arow] = a0.z; As[akg + 3][arow] = a0.w;
            As[akg + 4][arow] = a1.x; As[akg + 5][arow] = a1.y;
            As[akg + 6][arow] = a1.z; As[akg + 7][arow] = a1.w;
        }
        // Load B tile (16 x 128) directly Bs[k][n]
        {
            *(float4*)&Bs[brow][bcg]     = *(const float4*)&Bmat[(size_t)(k0 + brow) * N + n0 + bcg];
            *(float4*)&Bs[brow][bcg + 4] = *(const float4*)&Bmat[(size_t)(k0 + brow) * N + n0 + bcg + 4];
        }
        __syncthreads();
#pragma unroll
        for (int k = 0; k < 16; ++k) {
            const float4 a0 = *(const float4*)&As[k][ty * 8];
            const float4 a1 = *(const float4*)&As[k][ty * 8 + 4];
            const float4 b0 = *(const float4*)&Bs[k][tx * 8];
            const float4 b1 = *(const float4*)&Bs[k][tx * 8 + 4];
            const float av[8] = {a0.x, a0.y, a0.z, a0.w, a1.x, a1.y, a1.z, a1.w};
            const float bv[8] = {b0.x, b0.y, b0.z, b0.w, b1.x, b1.y, b1.z, b1.w};
#pragma unroll
            for (int i = 0; i < 8; ++i)
#pragma unroll
                for (int j = 0; j < 8; ++j)
                    acc[i][j] = fmaf(av[i], bv[j], acc[i][j]);
        }
    }
    // Epilogue: vectorized store
#pragma unroll
    for (int i = 0; i < 8; ++i) {
        float4 c0 = {acc[i][0], acc[i][1], acc[i][2], acc[i][3]};
        float4 c1 = {acc[i][4], acc[i][5], acc[i][6], acc[i][7]};
        float* dst = &Cmat[(size_t)(m0 + ty * 8 + i) * N + n0 + tx * 8];
        *(float4*)dst = c0;
        *(float4*)(dst + 4) = c1;
    }
}

// Fused QKV: blockIdx.z selects (Wq->Q, Wk->K, Wv->V). 768 blocks total.
__global__ __launch_bounds__(256) void gemm_qkv(const float* __restrict__ A,
                                                const float* __restrict__ B0,
                                                const float* __restrict__ B1,
                                                const float* __restrict__ B2,
                                                float* C0, float* C1, float* C2)
{
    const float* Bm = (blockIdx.z == 0) ? B0 : (blockIdx.z == 1 ? B1 : B2);
    float* Cm = (blockIdx.z == 0) ? C0 : (blockIdx.z == 1 ? C1 : C2);
    gemm_body(A, Bm, Cm, M_, HD, C_, blockIdx.y * 128, blockIdx.x * 128);
}

__global__ __launch_bounds__(256) void gemm_single(const float* __restrict__ A,
                                                   const float* __restrict__ Bm,
                                                   float* __restrict__ Cm,
                                                   int M, int N, int K)
{
    gemm_body(A, Bm, Cm, M, N, K, blockIdx.y * 128, blockIdx.x * 128);
}

// ---------------------------------------------------------------------------
// Per-head V column sums: vsum[b,h,d] = sum_j V[b,j,h*64+d]
// grid = B*NH blocks, 256 threads
// ---------------------------------------------------------------------------
__global__ __launch_bounds__(256) void vsum_k(const float* __restrict__ Vm,
                                              float* __restrict__ vsum)
{
    const int bh = blockIdx.x;
    const int b = bh / NH, h = bh % NH;
    const int d = threadIdx.x & 63;
    const int jg = threadIdx.x >> 6;
    float s = 0.f;
    for (int j = jg; j < S_; j += 4)
        s += Vm[(size_t)(b * S_ + j) * HD + h * 64 + d];
    __shared__ float red[4][64];
    red[jg][d] = s;
    __syncthreads();
    if (jg == 0)
        vsum[bh * 64 + d] = red[0][d] + red[1][d] + red[2][d] + red[3][d];
}

// ---------------------------------------------------------------------------
// Full-row max of scores: m[b,h,i] = max_j (q_i . k_j) * SCALE
// grid = (S/128, NH, B), 256 threads. GEMM-shaped, 128 q-rows x 64 j-cols/iter.
// ---------------------------------------------------------------------------
__global__ __launch_bounds__(256) void rowmax_k(const float* __restrict__ Q,
                                                const float* __restrict__ Km,
                                                float* __restrict__ mrow)
{
    __shared__ float Qs[64][132]; // [d][m]
    __shared__ float Ks[64][68];  // [d][j]
    const int tid = threadIdx.x;
    const int b = blockIdx.z, h = blockIdx.y;
    const int i0 = blockIdx.x * 128;

    // Load Q tile (128 rows x 64 d), transposed into Qs[d][m]
#pragma unroll
    for (int u = 0; u < 8; ++u) {
        const int g = u * 256 + tid;   // 0..2047 float4 index
        const int row = g >> 4;        // 0..127
        const int dg = (g & 15) * 4;   // 0..60
        const float4 v = *(const float4*)&Q[(size_t)(b * S_ + i0 + row) * HD + h * 64 + dg];
        Qs[dg + 0][row] = v.x; Qs[dg + 1][row] = v.y;
        Qs[dg + 2][row] = v.z; Qs[dg + 3][row] = v.w;
    }

    const int tx = tid & 15;  // cols tx*4 .. +3
    const int ty = tid >> 4;  // rows ty*8 .. +7
    float rmax[8];
#pragma unroll
    for (int r = 0; r < 8; ++r) rmax[r] = -1e30f;

    for (int j0 = 0; j0 < S_; j0 += 64) {
        __syncthreads();  // also publishes Qs on first iteration
        // Load K tile (64 rows x 64 d), transposed into Ks[d][j]
#pragma unroll
        for (int u = 0; u < 4; ++u) {
            const int g = u * 256 + tid;  // 0..1023
            const int jr = g >> 4;        // 0..63
            const int dg = (g & 15) * 4;
            const float4 v = *(const float4*)&Km[(size_t)(b * S_ + j0 + jr) * HD + h * 64 + dg];
            Ks[dg + 0][jr] = v.x; Ks[dg + 1][jr] = v.y;
            Ks[dg + 2][jr] = v.z; Ks[dg + 3][jr] = v.w;
        }
        __syncthreads();

        float acc[8][4];
#pragma unroll
        for (int r = 0; r < 8; ++r)
#pragma unroll
            for (int c = 0; c < 4; ++c) acc[r][c] = 0.f;

#pragma unroll 4
        for (int d = 0; d < 64; ++d) {
            const float4 a0 = *(const float4*)&Qs[d][ty * 8];
            const float4 a1 = *(const float4*)&Qs[d][ty * 8 + 4];
            const float4 bv = *(const float4*)&Ks[d][tx * 4];
            const float av[8] = {a0.x, a0.y, a0.z, a0.w, a1.x, a1.y, a1.z, a1.w};
            const float bb[4] = {bv.x, bv.y, bv.z, bv.w};
#pragma unroll
            for (int r = 0; r < 8; ++r)
#pragma unroll
                for (int c = 0; c < 4; ++c)
                    acc[r][c] = fmaf(av[r], bb[c], acc[r][c]);
        }
#pragma unroll
        for (int r = 0; r < 8; ++r)
#pragma unroll
            for (int c = 0; c < 4; ++c)
                rmax[r] = fmaxf(rmax[r], acc[r][c]);
    }

    // Reduce across tx (16 contiguous lanes per ty) and write
#pragma unroll
    for (int r = 0; r < 8; ++r) {
        float v = rmax[r];
        v = fmaxf(v, __shfl_xor(v, 1));
        v = fmaxf(v, __shfl_xor(v, 2));
        v = fmaxf(v, __shfl_xor(v, 4));
        v = fmaxf(v, __shfl_xor(v, 8));
        if (tx == 0)
            mrow[(size_t)(b * NH + h) * S_ + i0 + ty * 8 + r] = v * SCALE;
    }
}

// ---------------------------------------------------------------------------
// Band attention:
// out_i = (sum_band (e^{t}-1) v_j + vsum) / (sum_band (e^{t}-1) + S)
// t = exp(s_ij - m_i).  grid = (S/16, NH, B), 256 threads = 4 waves,
// wave handles 4 consecutive rows, lane = head dim d.
// NOTE: attn output may alias Q (each block reads only its own rows' q
// before writing the same addresses at the end).
// ---------------------------------------------------------------------------
__global__ __launch_bounds__(256) void band_attn(const float* __restrict__ Q,
                                                 const float* __restrict__ Km,
                                                 const float* __restrict__ Vm,
                                                 const float* __restrict__ mrow,
                                                 const float* __restrict__ vsum,
                                                 float* __restrict__ attn)
{
    const int b = blockIdx.z, h = blockIdx.y;
    const int i0 = blockIdx.x * 16;
    const int wv = threadIdx.x >> 6;
    const int lane = threadIdx.x & 63;
    const int headoff = h * 64 + lane;

    int irow[4];
    float q[4], m4[4], oacc[4], Z[4];
#pragma unroll
    for (int r = 0; r < 4; ++r) {
        irow[r] = i0 + wv * 4 + r;
        q[r] = Q[(size_t)(b * S_ + irow[r]) * HD + headoff];
        m4[r] = mrow[(size_t)(b * NH + h) * S_ + irow[r]];
        oacc[r] = 0.f;
        Z[r] = 0.f;
    }

    int jlo = i0 - 128;       if (jlo < 0) jlo = 0;
    int jhi = i0 + 15 + 127;  if (jhi > S_ - 1) jhi = S_ - 1;

    for (int j = jlo; j <= jhi; ++j) {
        const float kd = Km[(size_t)(b * S_ + j) * HD + headoff];
        const float vd = Vm[(size_t)(b * S_ + j) * HD + headoff];
#pragma unroll
        for (int r = 0; r < 4; ++r) {
            float p = q[r] * kd;
            p += __shfl_xor(p, 32);
            p += __shfl_xor(p, 16);
            p += __shfl_xor(p, 8);
            p += __shfl_xor(p, 4);
            p += __shfl_xor(p, 2);
            p += __shfl_xor(p, 1);
            const int dd = j - irow[r];
            if (dd >= -128 && dd <= 127) {
                const float t = __expf(p * SCALE - m4[r]);
                const float w = __expf(t) - 1.0f;
                Z[r] += w;
                oacc[r] = fmaf(w, vd, oacc[r]);
            }
        }
    }

    const float vs = vsum[(b * NH + h) * 64 + lane];
#pragma unroll
    for (int r = 0; r < 4; ++r)
        attn[(size_t)(b * S_ + irow[r]) * HD + headoff] =
            (oacc[r] + vs) / (Z[r] + (float)S_);
}

// ---------------------------------------------------------------------------
// Launch
// ---------------------------------------------------------------------------
extern "C" void kernel_launch(void* const* d_in, const int* in_sizes, int n_in,
                              void* d_out, int out_size, void* d_ws, size_t ws_size,
                              hipStream_t stream)
{
    const float* x  = (const float*)d_in[0];
    const float* Wq = (const float*)d_in[1];
    const float* Wk = (const float*)d_in[2];
    const float* Wv = (const float*)d_in[3];
    const float* Wo = (const float*)d_in[4];
    float* out = (float*)d_out;

    float* ws = (float*)d_ws;
    // Workspace layout (floats):
    //   Q    : [0,        4194304)   (also reused as attn output)
    //   K    : [4194304,  8388608)
    //   V    : [8388608, 12582912)
    //   mrow : [12582912, 12648448)   B*NH*S = 65536
    //   vsum : [12648448, 12650496)   B*NH*64 = 2048
    // total ~50.6 MB
    float* Q    = ws;
    float* K    = ws + 4194304;
    float* V    = ws + 8388608;
    float* mrow = ws + 12582912;
    float* vs   = ws + 12648448;
    float* attn = Q;  // safe alias: band_attn reads q before writing same rows

    // 1) Q,K,V projections (fused over blockIdx.z)
    gemm_qkv<<<dim3(HD / 128, M_ / 128, 3), 256, 0, stream>>>(x, Wq, Wk, Wv, Q, K, V);
    // 2) per-head V column sums
    vsum_k<<<B_ * NH, 256, 0, stream>>>(V, vs);
    // 3) full-row score max
    rowmax_k<<<dim3(S_ / 128, NH, B_), 256, 0, stream>>>(Q, K, mrow);
    // 4) band attention (writes attn = Q)
    band_attn<<<dim3(S_ / 16, NH, B_), 256, 0, stream>>>(Q, K, V, mrow, vs, attn);
    // 5) output projection
    gemm_single<<<dim3(C_ / 128, M_ / 128), 256, 0, stream>>>(attn, Wo, out, M_, C_, HD);
}

// Round 2
// 1030.507 us; speedup vs baseline: 2.0055x; 2.0055x over previous
//
#include <hip/hip_runtime.h>
#include <math.h>

// Problem constants
constexpr int B_  = 2;
constexpr int S_  = 2048;
constexpr int C_  = 1024;
constexpr int NH  = 16;
constexpr int DH  = 64;
constexpr int HD  = 1024;   // NH*DH
constexpr int M_  = B_ * S_;  // 4096
constexpr float SCALE = 0.125f; // 1/sqrt(64)

// ---------------------------------------------------------------------------
// Generic f32 GEMM body: C = A @ Bmat. A[M,K], Bmat[K,N], C[M,N], row-major.
// BM=BN=128, BK=16, 256 threads, 8x8 microtile.
// ---------------------------------------------------------------------------
__device__ __forceinline__ void gemm_body(const float* __restrict__ A,
                                          const float* __restrict__ Bmat,
                                          float* __restrict__ Cmat,
                                          int M, int N, int K,
                                          int m0, int n0)
{
    __shared__ float As[16][132];  // [k][m], padded
    __shared__ float Bs[16][132];  // [k][n], padded

    const int tid = threadIdx.x;
    const int tx = tid & 15;   // col group: cols tx*8 .. tx*8+7
    const int ty = tid >> 4;   // row group: rows ty*8 .. ty*8+7

    const int arow = tid >> 1;        // 0..127
    const int akg  = (tid & 1) * 8;   // 0 or 8
    const int brow = tid >> 4;        // 0..15
    const int bcg  = (tid & 15) * 8;  // 0..120

    float acc[8][8];
#pragma unroll
    for (int i = 0; i < 8; ++i)
#pragma unroll
        for (int j = 0; j < 8; ++j) acc[i][j] = 0.f;

    for (int k0 = 0; k0 < K; k0 += 16) {
        __syncthreads();
        {
            const float4 a0 = *(const float4*)&A[(size_t)(m0 + arow) * K + k0 + akg];
            const float4 a1 = *(const float4*)&A[(size_t)(m0 + arow) * K + k0 + akg + 4];
            As[akg + 0][arow] = a0.x; As[akg + 1][arow] = a0.y;
            As[akg + 2][arow] = a0.z; As[akg + 3][arow] = a0.w;
            As[akg + 4][arow] = a1.x; As[akg + 5][arow] = a1.y;
            As[akg + 6][arow] = a1.z; As[akg + 7][arow] = a1.w;
        }
        {
            *(float4*)&Bs[brow][bcg]     = *(const float4*)&Bmat[(size_t)(k0 + brow) * N + n0 + bcg];
            *(float4*)&Bs[brow][bcg + 4] = *(const float4*)&Bmat[(size_t)(k0 + brow) * N + n0 + bcg + 4];
        }
        __syncthreads();
#pragma unroll
        for (int k = 0; k < 16; ++k) {
            const float4 a0 = *(const float4*)&As[k][ty * 8];
            const float4 a1 = *(const float4*)&As[k][ty * 8 + 4];
            const float4 b0 = *(const float4*)&Bs[k][tx * 8];
            const float4 b1 = *(const float4*)&Bs[k][tx * 8 + 4];
            const float av[8] = {a0.x, a0.y, a0.z, a0.w, a1.x, a1.y, a1.z, a1.w};
            const float bv[8] = {b0.x, b0.y, b0.z, b0.w, b1.x, b1.y, b1.z, b1.w};
#pragma unroll
            for (int i = 0; i < 8; ++i)
#pragma unroll
                for (int j = 0; j < 8; ++j)
                    acc[i][j] = fmaf(av[i], bv[j], acc[i][j]);
        }
    }
#pragma unroll
    for (int i = 0; i < 8; ++i) {
        float4 c0 = {acc[i][0], acc[i][1], acc[i][2], acc[i][3]};
        float4 c1 = {acc[i][4], acc[i][5], acc[i][6], acc[i][7]};
        float* dst = &Cmat[(size_t)(m0 + ty * 8 + i) * N + n0 + tx * 8];
        *(float4*)dst = c0;
        *(float4*)(dst + 4) = c1;
    }
}

__global__ __launch_bounds__(256) void gemm_qkv(const float* __restrict__ A,
                                                const float* __restrict__ B0,
                                                const float* __restrict__ B1,
                                                const float* __restrict__ B2,
                                                float* C0, float* C1, float* C2)
{
    const float* Bm = (blockIdx.z == 0) ? B0 : (blockIdx.z == 1 ? B1 : B2);
    float* Cm = (blockIdx.z == 0) ? C0 : (blockIdx.z == 1 ? C1 : C2);
    gemm_body(A, Bm, Cm, M_, HD, C_, blockIdx.y * 128, blockIdx.x * 128);
}

__global__ __launch_bounds__(256) void gemm_single(const float* __restrict__ A,
                                                   const float* __restrict__ Bm,
                                                   float* __restrict__ Cm,
                                                   int M, int N, int K)
{
    gemm_body(A, Bm, Cm, M, N, K, blockIdx.y * 128, blockIdx.x * 128);
}

// ---------------------------------------------------------------------------
// Per-head V column sums
// ---------------------------------------------------------------------------
__global__ __launch_bounds__(256) void vsum_k(const float* __restrict__ Vm,
                                              float* __restrict__ vsum)
{
    const int bh = blockIdx.x;
    const int b = bh / NH, h = bh % NH;
    const int d = threadIdx.x & 63;
    const int jg = threadIdx.x >> 6;
    float s = 0.f;
    for (int j = jg; j < S_; j += 4)
        s += Vm[(size_t)(b * S_ + j) * HD + h * 64 + d];
    __shared__ float red[4][64];
    red[jg][d] = s;
    __syncthreads();
    if (jg == 0)
        vsum[bh * 64 + d] = red[0][d] + red[1][d] + red[2][d] + red[3][d];
}

// ---------------------------------------------------------------------------
// Full-row score max
// ---------------------------------------------------------------------------
__global__ __launch_bounds__(256) void rowmax_k(const float* __restrict__ Q,
                                                const float* __restrict__ Km,
                                                float* __restrict__ mrow)
{
    __shared__ float Qs[64][132]; // [d][m]
    __shared__ float Ks[64][68];  // [d][j]
    const int tid = threadIdx.x;
    const int b = blockIdx.z, h = blockIdx.y;
    const int i0 = blockIdx.x * 128;

#pragma unroll
    for (int u = 0; u < 8; ++u) {
        const int g = u * 256 + tid;
        const int row = g >> 4;
        const int dg = (g & 15) * 4;
        const float4 v = *(const float4*)&Q[(size_t)(b * S_ + i0 + row) * HD + h * 64 + dg];
        Qs[dg + 0][row] = v.x; Qs[dg + 1][row] = v.y;
        Qs[dg + 2][row] = v.z; Qs[dg + 3][row] = v.w;
    }

    const int tx = tid & 15;
    const int ty = tid >> 4;
    float rmax[8];
#pragma unroll
    for (int r = 0; r < 8; ++r) rmax[r] = -1e30f;

    for (int j0 = 0; j0 < S_; j0 += 64) {
        __syncthreads();
#pragma unroll
        for (int u = 0; u < 4; ++u) {
            const int g = u * 256 + tid;
            const int jr = g >> 4;
            const int dg = (g & 15) * 4;
            const float4 v = *(const float4*)&Km[(size_t)(b * S_ + j0 + jr) * HD + h * 64 + dg];
            Ks[dg + 0][jr] = v.x; Ks[dg + 1][jr] = v.y;
            Ks[dg + 2][jr] = v.z; Ks[dg + 3][jr] = v.w;
        }
        __syncthreads();

        float acc[8][4];
#pragma unroll
        for (int r = 0; r < 8; ++r)
#pragma unroll
            for (int c = 0; c < 4; ++c) acc[r][c] = 0.f;

#pragma unroll 4
        for (int d = 0; d < 64; ++d) {
            const float4 a0 = *(const float4*)&Qs[d][ty * 8];
            const float4 a1 = *(const float4*)&Qs[d][ty * 8 + 4];
            const float4 bv = *(const float4*)&Ks[d][tx * 4];
            const float av[8] = {a0.x, a0.y, a0.z, a0.w, a1.x, a1.y, a1.z, a1.w};
            const float bb[4] = {bv.x, bv.y, bv.z, bv.w};
#pragma unroll
            for (int r = 0; r < 8; ++r)
#pragma unroll
                for (int c = 0; c < 4; ++c)
                    acc[r][c] = fmaf(av[r], bb[c], acc[r][c]);
        }
#pragma unroll
        for (int r = 0; r < 8; ++r)
#pragma unroll
            for (int c = 0; c < 4; ++c)
                rmax[r] = fmaxf(rmax[r], acc[r][c]);
    }

#pragma unroll
    for (int r = 0; r < 8; ++r) {
        float v = rmax[r];
        v = fmaxf(v, __shfl_xor(v, 1));
        v = fmaxf(v, __shfl_xor(v, 2));
        v = fmaxf(v, __shfl_xor(v, 4));
        v = fmaxf(v, __shfl_xor(v, 8));
        if (tx == 0)
            mrow[(size_t)(b * NH + h) * S_ + i0 + ty * 8 + r] = v * SCALE;
    }
}

// ---------------------------------------------------------------------------
// Band attention, GEMM-shaped rewrite.
// Block: 256 threads, one (b,h) and 32 query rows. 5 chunks of 64 keys
// covering j in [i0-128, i0+192) ⊇ band. Two LDS-tiled GEMM phases
// (scores, then W@V) with the double-exp weight transform in registers.
//   out_i = (sum_band (e^{t}-1) v_j + vsum) / (sum_band (e^{t}-1) + S)
// attn may alias Q: block reads only its own Q rows (staged in LDS first).
// ---------------------------------------------------------------------------
__global__ __launch_bounds__(256) void band_attn(const float* __restrict__ Q,
                                                 const float* __restrict__ Km,
                                                 const float* __restrict__ Vm,
                                                 const float* __restrict__ mrow,
                                                 const float* __restrict__ vsum,
                                                 float* __restrict__ attn)
{
    __shared__ float Qs[32][68];  // [i][d]
    __shared__ float Ks[64][68];  // TRANSPOSED: [d][j]  (j contiguous -> 2-way banks)
    __shared__ float Vs[64][68];  // [j][d]
    __shared__ float Ws[32][68];  // [i][j] weights

    const int tid = threadIdx.x;
    const int b = blockIdx.z, h = blockIdx.y;
    const int i0 = blockIdx.x * 32;
    const int ty = tid >> 4;   // 0..15 -> rows ty*2, ty*2+1
    const int tx = tid & 15;   // cols tx*4 .. +3

    // Stage Q tile [32][64]
#pragma unroll
    for (int u = 0; u < 2; ++u) {
        const int idx = u * 256 + tid;   // float4 index 0..511
        const int row = idx >> 4;        // 0..31
        const int dg  = (idx & 15) * 4;
        *(float4*)&Qs[row][dg] =
            *(const float4*)&Q[(size_t)(b * S_ + i0 + row) * HD + h * 64 + dg];
    }

    float mr[2], Zacc[2] = {0.f, 0.f};
    mr[0] = mrow[(size_t)(b * NH + h) * S_ + i0 + ty * 2];
    mr[1] = mrow[(size_t)(b * NH + h) * S_ + i0 + ty * 2 + 1];

    float acco[2][4];
#pragma unroll
    for (int r = 0; r < 2; ++r)
#pragma unroll
        for (int c = 0; c < 4; ++c) acco[r][c] = 0.f;

    // K/V chunk-loader indices: 4 threads per j-row, 16 d each
    const int ljj = tid >> 2;          // 0..63
    const int ldg = (tid & 3) * 16;    // 0,16,32,48

    for (int cb = 0; cb < 5; ++cb) {
        const int jbase = i0 - 128 + cb * 64;
        if (jbase + 64 <= 0 || jbase >= S_) continue;  // uniform

        __syncthreads();  // previous chunk's readers done
        {
            const int j = jbase + ljj;
            float4 k4[4], v4[4];
            if (j >= 0 && j < S_) {
                const float* ksrc = &Km[(size_t)(b * S_ + j) * HD + h * 64 + ldg];
                const float* vsrc = &Vm[(size_t)(b * S_ + j) * HD + h * 64 + ldg];
#pragma unroll
                for (int u = 0; u < 4; ++u) {
                    k4[u] = *(const float4*)(ksrc + u * 4);
                    v4[u] = *(const float4*)(vsrc + u * 4);
                }
            } else {
#pragma unroll
                for (int u = 0; u < 4; ++u) {
                    k4[u] = make_float4(0.f, 0.f, 0.f, 0.f);
                    v4[u] = make_float4(0.f, 0.f, 0.f, 0.f);
                }
            }
            // K transposed scatter
#pragma unroll
            for (int u = 0; u < 4; ++u) {
                Ks[ldg + u * 4 + 0][ljj] = k4[u].x;
                Ks[ldg + u * 4 + 1][ljj] = k4[u].y;
                Ks[ldg + u * 4 + 2][ljj] = k4[u].z;
                Ks[ldg + u * 4 + 3][ljj] = k4[u].w;
                *(float4*)&Vs[ljj][ldg + u * 4] = v4[u];
            }
        }
        __syncthreads();

        // --- scores: sc[2][4] = Q[rows] . K[cols] ---
        float sc[2][4];
#pragma unroll
        for (int r = 0; r < 2; ++r)
#pragma unroll
            for (int c = 0; c < 4; ++c) sc[r][c] = 0.f;

#pragma unroll 4
        for (int d4 = 0; d4 < 64; d4 += 4) {
            const float4 q0 = *(const float4*)&Qs[ty * 2 + 0][d4];
            const float4 q1 = *(const float4*)&Qs[ty * 2 + 1][d4];
            const float4 k0 = *(const float4*)&Ks[d4 + 0][tx * 4];
            const float4 k1 = *(const float4*)&Ks[d4 + 1][tx * 4];
            const float4 k2 = *(const float4*)&Ks[d4 + 2][tx * 4];
            const float4 k3 = *(const float4*)&Ks[d4 + 3][tx * 4];
            const float qa[2][4] = {{q0.x, q0.y, q0.z, q0.w}, {q1.x, q1.y, q1.z, q1.w}};
            const float kk[4][4] = {{k0.x, k0.y, k0.z, k0.w}, {k1.x, k1.y, k1.z, k1.w},
                                    {k2.x, k2.y, k2.z, k2.w}, {k3.x, k3.y, k3.z, k3.w}};
#pragma unroll
            for (int r = 0; r < 2; ++r)
#pragma unroll
                for (int dd = 0; dd < 4; ++dd)
#pragma unroll
                    for (int c = 0; c < 4; ++c)
                        sc[r][c] = fmaf(qa[r][dd], kk[dd][c], sc[r][c]);
        }

        // --- weights: w = exp(exp(s*SCALE - m)) - 1, masked ---
        float w[2][4];
#pragma unroll
        for (int r = 0; r < 2; ++r) {
            const int ig = i0 + ty * 2 + r;
#pragma unroll
            for (int c = 0; c < 4; ++c) {
                const int jg = jbase + tx * 4 + c;
                const int dd = jg - ig;
                const bool ok = (jg >= 0) && (jg < S_) && (dd >= -128) && (dd <= 127);
                const float t = __expf(sc[r][c] * SCALE - mr[r]);
                const float wv = ok ? (__expf(t) - 1.0f) : 0.0f;
                w[r][c] = wv;
                Zacc[r] += wv;
            }
        }
        *(float4*)&Ws[ty * 2 + 0][tx * 4] = make_float4(w[0][0], w[0][1], w[0][2], w[0][3]);
        *(float4*)&Ws[ty * 2 + 1][tx * 4] = make_float4(w[1][0], w[1][1], w[1][2], w[1][3]);
        __syncthreads();

        // --- output: O[rows][tx*4..] += W[rows][:] @ V[:][tx*4..] ---
#pragma unroll 4
        for (int j4 = 0; j4 < 64; j4 += 4) {
            const float4 w0 = *(const float4*)&Ws[ty * 2 + 0][j4];
            const float4 w1 = *(const float4*)&Ws[ty * 2 + 1][j4];
            const float4 v0 = *(const float4*)&Vs[j4 + 0][tx * 4];
            const float4 v1 = *(const float4*)&Vs[j4 + 1][tx * 4];
            const float4 v2 = *(const float4*)&Vs[j4 + 2][tx * 4];
            const float4 v3 = *(const float4*)&Vs[j4 + 3][tx * 4];
            const float wa[2][4] = {{w0.x, w0.y, w0.z, w0.w}, {w1.x, w1.y, w1.z, w1.w}};
            const float vv[4][4] = {{v0.x, v0.y, v0.z, v0.w}, {v1.x, v1.y, v1.z, v1.w},
                                    {v2.x, v2.y, v2.z, v2.w}, {v3.x, v3.y, v3.z, v3.w}};
#pragma unroll
            for (int r = 0; r < 2; ++r)
#pragma unroll
                for (int jj = 0; jj < 4; ++jj)
#pragma unroll
                    for (int c = 0; c < 4; ++c)
                        acco[r][c] = fmaf(wa[r][jj], vv[jj][c], acco[r][c]);
        }
    }

    // Z row-sum across the 16 tx lanes of each row group
#pragma unroll
    for (int r = 0; r < 2; ++r) {
        float z = Zacc[r];
        z += __shfl_xor(z, 1);
        z += __shfl_xor(z, 2);
        z += __shfl_xor(z, 4);
        z += __shfl_xor(z, 8);
        Zacc[r] = z;
    }

    const float4 vsv = *(const float4*)&vsum[(b * NH + h) * 64 + tx * 4];
#pragma unroll
    for (int r = 0; r < 2; ++r) {
        const float invden = 1.0f / (Zacc[r] + (float)S_);
        float4 o;
        o.x = (acco[r][0] + vsv.x) * invden;
        o.y = (acco[r][1] + vsv.y) * invden;
        o.z = (acco[r][2] + vsv.z) * invden;
        o.w = (acco[r][3] + vsv.w) * invden;
        *(float4*)&attn[(size_t)(b * S_ + i0 + ty * 2 + r) * HD + h * 64 + tx * 4] = o;
    }
}

// ---------------------------------------------------------------------------
// Launch
// ---------------------------------------------------------------------------
extern "C" void kernel_launch(void* const* d_in, const int* in_sizes, int n_in,
                              void* d_out, int out_size, void* d_ws, size_t ws_size,
                              hipStream_t stream)
{
    const float* x  = (const float*)d_in[0];
    const float* Wq = (const float*)d_in[1];
    const float* Wk = (const float*)d_in[2];
    const float* Wv = (const float*)d_in[3];
    const float* Wo = (const float*)d_in[4];
    float* out = (float*)d_out;

    float* ws = (float*)d_ws;
    float* Q    = ws;
    float* K    = ws + 4194304;
    float* V    = ws + 8388608;
    float* mrow = ws + 12582912;
    float* vs   = ws + 12648448;
    float* attn = Q;  // safe alias: band_attn stages its own Q rows first

    gemm_qkv<<<dim3(HD / 128, M_ / 128, 3), 256, 0, stream>>>(x, Wq, Wk, Wv, Q, K, V);
    vsum_k<<<B_ * NH, 256, 0, stream>>>(V, vs);
    rowmax_k<<<dim3(S_ / 128, NH, B_), 256, 0, stream>>>(Q, K, mrow);
    band_attn<<<dim3(S_ / 32, NH, B_), 256, 0, stream>>>(Q, K, V, mrow, vs, attn);
    gemm_single<<<dim3(C_ / 128, M_ / 128), 256, 0, stream>>>(attn, Wo, out, M_, C_, HD);
}

// Round 3
// 229.787 us; speedup vs baseline: 8.9937x; 4.4846x over previous
//
#include <hip/hip_runtime.h>
#include <math.h>

typedef __bf16 bf16_t;
typedef bf16_t bf16x8 __attribute__((ext_vector_type(8)));
typedef bf16_t bf16x4 __attribute__((ext_vector_type(4)));
typedef float f32x4 __attribute__((ext_vector_type(4)));

constexpr int S_  = 2048;
constexpr int NH  = 16;
constexpr int HD  = 1024;
constexpr int M_  = 4096;     // B*S
constexpr float SCALE = 0.125f;  // 1/sqrt(64)

#define MFMA_B16(a, b, c) __builtin_amdgcn_mfma_f32_16x16x32_bf16(a, b, c, 0, 0, 0)

// ---------------------------------------------------------------------------
// cast x (f32[4096][1024]) -> bf16, same layout
// ---------------------------------------------------------------------------
__global__ __launch_bounds__(256) void cast_x(const float* __restrict__ x,
                                              bf16_t* __restrict__ xb)
{
    const int g = blockIdx.x * 256 + threadIdx.x;  // float4 index, 1048576 total
    const float4 v = ((const float4*)x)[g];
    bf16x4 o;
    o[0] = (bf16_t)v.x; o[1] = (bf16_t)v.y; o[2] = (bf16_t)v.z; o[3] = (bf16_t)v.w;
    *(bf16x4*)&xb[(size_t)g * 4] = o;
}

// ---------------------------------------------------------------------------
// transpose-cast weights: Wt[n][k] = (bf16)W[k][n]. 32x32 tiles via LDS.
// grid (32, 32, 4) : z picks Wq/Wk/Wv/Wo
// ---------------------------------------------------------------------------
__global__ __launch_bounds__(256) void tcast_w(const float* __restrict__ Wq,
                                               const float* __restrict__ Wk,
                                               const float* __restrict__ Wv,
                                               const float* __restrict__ Wo,
                                               bf16_t* __restrict__ Wqt,
                                               bf16_t* __restrict__ Wkt,
                                               bf16_t* __restrict__ Wvt,
                                               bf16_t* __restrict__ Wot)
{
    const float* src = (blockIdx.z == 0) ? Wq : (blockIdx.z == 1) ? Wk
                      : (blockIdx.z == 2) ? Wv : Wo;
    bf16_t* dst = (blockIdx.z == 0) ? Wqt : (blockIdx.z == 1) ? Wkt
                 : (blockIdx.z == 2) ? Wvt : Wot;
    const int k0 = blockIdx.y * 32, n0 = blockIdx.x * 32;
    __shared__ float T[32][33];
    const int r  = threadIdx.x >> 3;
    const int c4 = (threadIdx.x & 7) * 4;
    const float4 v = *(const float4*)&src[(size_t)(k0 + r) * 1024 + n0 + c4];
    T[r][c4 + 0] = v.x; T[r][c4 + 1] = v.y; T[r][c4 + 2] = v.z; T[r][c4 + 3] = v.w;
    __syncthreads();
    bf16x4 o;
#pragma unroll
    for (int u = 0; u < 4; ++u) o[u] = (bf16_t)T[c4 + u][r];
    *(bf16x4*)&dst[(size_t)(n0 + r) * 1024 + k0 + c4] = o;
}

// ---------------------------------------------------------------------------
// bf16 MFMA GEMM: C = A[M][1024] @ Bt[N][1024]^T, 128x128 tile, BK=32,
// 256 threads = 4 waves (2x2 of 64x64), 16x16x32 MFMA, 4x4 tiles/wave.
// MODE 0: write f32 row-major [.][1024].  MODE 1: write bf16 head layout
// [b][h][s][64] (m = b*2048+s, n = h*64+d).
// ---------------------------------------------------------------------------
template <int MODE>
__device__ __forceinline__ void mfma_gemm_body(const bf16_t* __restrict__ A,
                                               const bf16_t* __restrict__ Bt,
                                               void* __restrict__ dst,
                                               int m0, int n0)
{
    __shared__ bf16_t As[128][40];  // [m][k], pad->2-way banks on b128 reads
    __shared__ bf16_t Bs[128][40];  // [n][k]

    const int tid  = threadIdx.x;
    const int lane = tid & 63;
    const int wid  = tid >> 6;
    const int l15  = lane & 15;
    const int quad = lane >> 4;
    const int wm = (wid & 1) * 64;
    const int wn = (wid >> 1) * 64;

    const int r0  = tid >> 2;        // 0..63
    const int k80 = (tid & 3) * 8;   // 0,8,16,24

    f32x4 acc[4][4];
#pragma unroll
    for (int i = 0; i < 4; ++i)
#pragma unroll
        for (int j = 0; j < 4; ++j) acc[i][j] = (f32x4){0.f, 0.f, 0.f, 0.f};

    bf16x8 a0 = *(const bf16x8*)&A [(size_t)(m0 + r0)      * 1024 + k80];
    bf16x8 a1 = *(const bf16x8*)&A [(size_t)(m0 + r0 + 64) * 1024 + k80];
    bf16x8 b0 = *(const bf16x8*)&Bt[(size_t)(n0 + r0)      * 1024 + k80];
    bf16x8 b1 = *(const bf16x8*)&Bt[(size_t)(n0 + r0 + 64) * 1024 + k80];

    for (int k0 = 0; k0 < 1024; k0 += 32) {
        __syncthreads();
        *(bf16x8*)&As[r0][k80]      = a0;
        *(bf16x8*)&As[r0 + 64][k80] = a1;
        *(bf16x8*)&Bs[r0][k80]      = b0;
        *(bf16x8*)&Bs[r0 + 64][k80] = b1;
        __syncthreads();
        if (k0 + 32 < 1024) {
            a0 = *(const bf16x8*)&A [(size_t)(m0 + r0)      * 1024 + k0 + 32 + k80];
            a1 = *(const bf16x8*)&A [(size_t)(m0 + r0 + 64) * 1024 + k0 + 32 + k80];
            b0 = *(const bf16x8*)&Bt[(size_t)(n0 + r0)      * 1024 + k0 + 32 + k80];
            b1 = *(const bf16x8*)&Bt[(size_t)(n0 + r0 + 64) * 1024 + k0 + 32 + k80];
        }
        bf16x8 af[4], bfr[4];
#pragma unroll
        for (int mt = 0; mt < 4; ++mt)
            af[mt] = *(const bf16x8*)&As[wm + mt * 16 + l15][quad * 8];
#pragma unroll
        for (int nt = 0; nt < 4; ++nt)
            bfr[nt] = *(const bf16x8*)&Bs[wn + nt * 16 + l15][quad * 8];
#pragma unroll
        for (int mt = 0; mt < 4; ++mt)
#pragma unroll
            for (int nt = 0; nt < 4; ++nt)
                acc[mt][nt] = MFMA_B16(af[mt], bfr[nt], acc[mt][nt]);
    }

#pragma unroll
    for (int mt = 0; mt < 4; ++mt)
#pragma unroll
        for (int nt = 0; nt < 4; ++nt) {
            const int nI = n0 + wn + nt * 16 + l15;
#pragma unroll
            for (int reg = 0; reg < 4; ++reg) {
                const int mI = m0 + wm + mt * 16 + quad * 4 + reg;
                const float v = acc[mt][nt][reg];
                if (MODE == 0) {
                    ((float*)dst)[(size_t)mI * 1024 + nI] = v;
                } else {
                    const int b = mI >> 11, s = mI & 2047;
                    const int h = nI >> 6,  d = nI & 63;
                    ((bf16_t*)dst)[(size_t)(b * 16 + h) * 131072 + s * 64 + d] = (bf16_t)v;
                }
            }
        }
}

__global__ __launch_bounds__(256) void gemm_qkv_mfma(const bf16_t* __restrict__ xb,
                                                     const bf16_t* __restrict__ Wqt,
                                                     const bf16_t* __restrict__ Wkt,
                                                     const bf16_t* __restrict__ Wvt,
                                                     bf16_t* Qh, bf16_t* Kh, bf16_t* Vh)
{
    const bf16_t* Bt = (blockIdx.z == 0) ? Wqt : (blockIdx.z == 1) ? Wkt : Wvt;
    bf16_t* dst = (blockIdx.z == 0) ? Qh : (blockIdx.z == 1) ? Kh : Vh;
    mfma_gemm_body<1>(xb, Bt, dst, blockIdx.y * 128, blockIdx.x * 128);
}

__global__ __launch_bounds__(256) void gemm_out_mfma(const bf16_t* __restrict__ attn,
                                                     const bf16_t* __restrict__ Wot,
                                                     float* __restrict__ out)
{
    mfma_gemm_body<0>(attn, Wot, out, blockIdx.y * 128, blockIdx.x * 128);
}

// ---------------------------------------------------------------------------
// partial V column sums: vsp[bh][seg][d] = sum_{j in seg*256..} Vh[bh][j][d]
// grid = 32*8 blocks
// ---------------------------------------------------------------------------
__global__ __launch_bounds__(256) void vsum_k(const bf16_t* __restrict__ Vh,
                                              float* __restrict__ vsp)
{
    const int bh = blockIdx.x >> 3, seg = blockIdx.x & 7;
    const int d = threadIdx.x & 63, jg = threadIdx.x >> 6;
    float s = 0.f;
    const int jb = seg * 256;
    for (int j = jb + jg; j < jb + 256; j += 4)
        s += (float)Vh[(size_t)bh * 131072 + j * 64 + d];
    __shared__ float red[4][64];
    red[jg][d] = s;
    __syncthreads();
    if (jg == 0)
        vsp[(bh * 8 + seg) * 64 + d] = red[0][d] + red[1][d] + red[2][d] + red[3][d];
}

// ---------------------------------------------------------------------------
// rowmax via MFMA: mrow[bh][i] = SCALE * max_j (q_i . k_j)
// grid (16, 16, 2); block 256 = 4 waves; block does 128 q-rows, scans S keys.
// wave w handles rows w*32..w*32+31 (mt=2), 64 j-cols (nt=4) per chunk.
// ---------------------------------------------------------------------------
__global__ __launch_bounds__(256) void rowmax_mfma(const bf16_t* __restrict__ Qh,
                                                   const bf16_t* __restrict__ Kh,
                                                   float* __restrict__ mrow)
{
    __shared__ bf16_t Qs[128][72];  // [i][k]
    __shared__ bf16_t Ks[64][72];   // [j][k]
    const int tid = threadIdx.x;
    const int lane = tid & 63, wid = tid >> 6;
    const int l15 = lane & 15, quad = lane >> 4;
    const int bh = blockIdx.z * 16 + blockIdx.y;
    const int i0 = blockIdx.x * 128;
    const bf16_t* Qb = Qh + (size_t)bh * 131072;
    const bf16_t* Kb = Kh + (size_t)bh * 131072;

#pragma unroll
    for (int u = 0; u < 4; ++u) {
        const int c = tid + 256 * u;
        const int row = c >> 3, k8 = (c & 7) * 8;
        *(bf16x8*)&Qs[row][k8] = *(const bf16x8*)&Qb[(size_t)(i0 + row) * 64 + k8];
    }

    float rmax[2][4];
#pragma unroll
    for (int mt = 0; mt < 2; ++mt)
#pragma unroll
        for (int r = 0; r < 4; ++r) rmax[mt][r] = -3.0e38f;

    for (int j0 = 0; j0 < S_; j0 += 64) {
        __syncthreads();
#pragma unroll
        for (int u = 0; u < 2; ++u) {
            const int c = tid + 256 * u;
            const int row = c >> 3, k8 = (c & 7) * 8;
            *(bf16x8*)&Ks[row][k8] = *(const bf16x8*)&Kb[(size_t)(j0 + row) * 64 + k8];
        }
        __syncthreads();

        f32x4 acc[2][4];
#pragma unroll
        for (int mt = 0; mt < 2; ++mt)
#pragma unroll
            for (int nt = 0; nt < 4; ++nt) acc[mt][nt] = (f32x4){0.f, 0.f, 0.f, 0.f};

#pragma unroll
        for (int ks = 0; ks < 2; ++ks) {
            bf16x8 af[2], bfr[4];
#pragma unroll
            for (int mt = 0; mt < 2; ++mt)
                af[mt] = *(const bf16x8*)&Qs[wid * 32 + mt * 16 + l15][ks * 32 + quad * 8];
#pragma unroll
            for (int nt = 0; nt < 4; ++nt)
                bfr[nt] = *(const bf16x8*)&Ks[nt * 16 + l15][ks * 32 + quad * 8];
#pragma unroll
            for (int mt = 0; mt < 2; ++mt)
#pragma unroll
                for (int nt = 0; nt < 4; ++nt)
                    acc[mt][nt] = MFMA_B16(af[mt], bfr[nt], acc[mt][nt]);
        }
#pragma unroll
        for (int mt = 0; mt < 2; ++mt)
#pragma unroll
            for (int nt = 0; nt < 4; ++nt)
#pragma unroll
                for (int r = 0; r < 4; ++r)
                    rmax[mt][r] = fmaxf(rmax[mt][r], acc[mt][nt][r]);
    }

#pragma unroll
    for (int mt = 0; mt < 2; ++mt)
#pragma unroll
        for (int r = 0; r < 4; ++r) {
            float v = rmax[mt][r];
            v = fmaxf(v, __shfl_xor(v, 1));
            v = fmaxf(v, __shfl_xor(v, 2));
            v = fmaxf(v, __shfl_xor(v, 4));
            v = fmaxf(v, __shfl_xor(v, 8));
            if (l15 == 0)
                mrow[(size_t)bh * S_ + i0 + wid * 32 + mt * 16 + quad * 4 + r] = v * SCALE;
        }
}

// ---------------------------------------------------------------------------
// band attention via MFMA. grid (32, 16, 2); block = 64 q-rows of one (b,h).
// 5 chunks of 64 keys cover [i0-128, i0+192). Per chunk: scores MFMA,
// double-exp + band mask in regs, W -> LDS (C-layout -> A-layout), W@V MFMA.
// out_i = (sum w*v + vsum) / (sum w + 2048); w = exp(exp(s*SC - m)) - 1.
// ---------------------------------------------------------------------------
__global__ __launch_bounds__(256) void band_mfma(const bf16_t* __restrict__ Qh,
                                                 const bf16_t* __restrict__ Kh,
                                                 const bf16_t* __restrict__ Vh,
                                                 const float* __restrict__ mrow,
                                                 const float* __restrict__ vsp,
                                                 bf16_t* __restrict__ attn)
{
    __shared__ bf16_t Qs[64][72];  // [i][k]
    __shared__ bf16_t Ks[64][72];  // [j][k]
    __shared__ bf16_t Vt[64][72];  // [d][j]  (B-operand for W@V)
    __shared__ bf16_t Ws[64][72];  // [i][j]  (A-operand weights)

    const int tid = threadIdx.x;
    const int lane = tid & 63, wid = tid >> 6;
    const int l15 = lane & 15, quad = lane >> 4;
    const int b = blockIdx.z, h = blockIdx.y;
    const int bh = b * 16 + h;
    const int i0 = blockIdx.x * 64;
    const bf16_t* Qb = Qh + (size_t)bh * 131072;
    const bf16_t* Kb = Kh + (size_t)bh * 131072;
    const bf16_t* Vb = Vh + (size_t)bh * 131072;

#pragma unroll
    for (int u = 0; u < 2; ++u) {
        const int c = tid + 256 * u;
        const int row = c >> 3, k8 = (c & 7) * 8;
        *(bf16x8*)&Qs[row][k8] = *(const bf16x8*)&Qb[(size_t)(i0 + row) * 64 + k8];
    }

    float mreg[4];
#pragma unroll
    for (int r = 0; r < 4; ++r)
        mreg[r] = mrow[(size_t)bh * S_ + i0 + wid * 16 + quad * 4 + r];

    float vsd[4];
#pragma unroll
    for (int nt = 0; nt < 4; ++nt) {
        float s = 0.f;
#pragma unroll
        for (int seg = 0; seg < 8; ++seg)
            s += vsp[(bh * 8 + seg) * 64 + nt * 16 + l15];
        vsd[nt] = s;
    }

    f32x4 accO[4];
#pragma unroll
    for (int nt = 0; nt < 4; ++nt) accO[nt] = (f32x4){0.f, 0.f, 0.f, 0.f};
    float zp[4] = {0.f, 0.f, 0.f, 0.f};

    const int vjj = tid >> 2;          // 0..63 : j row for Vt staging
    const int vd0 = (tid & 3) * 16;    // 16 d per thread

    for (int cb = 0; cb < 5; ++cb) {
        const int jb = i0 - 128 + cb * 64;
        if (jb + 64 <= 0 || jb >= S_) continue;  // block-uniform

        __syncthreads();  // prior chunk's LDS readers (incl. Ws) done
        // stage K[j][k]
#pragma unroll
        for (int u = 0; u < 2; ++u) {
            const int c = tid + 256 * u;
            const int row = c >> 3, k8 = (c & 7) * 8;
            const int j = jb + row;
            bf16x8 kv;
            if (j >= 0 && j < S_) kv = *(const bf16x8*)&Kb[(size_t)j * 64 + k8];
            else { bf16_t z = (bf16_t)0.f; kv = (bf16x8){z,z,z,z,z,z,z,z}; }
            *(bf16x8*)&Ks[row][k8] = kv;
        }
        // stage V transposed: Vt[d][j]
        {
            const int j = jb + vjj;
            const bool ok = (j >= 0 && j < S_);
#pragma unroll
            for (int u = 0; u < 2; ++u) {
                bf16x8 vv;
                if (ok) vv = *(const bf16x8*)&Vb[(size_t)j * 64 + vd0 + u * 8];
                else { bf16_t z = (bf16_t)0.f; vv = (bf16x8){z,z,z,z,z,z,z,z}; }
#pragma unroll
                for (int e = 0; e < 8; ++e)
                    Vt[vd0 + u * 8 + e][vjj] = vv[e];
            }
        }
        __syncthreads();

        // scores: wave w rows i0+w*16..+15  x  64 j
        f32x4 sacc[4];
#pragma unroll
        for (int nt = 0; nt < 4; ++nt) sacc[nt] = (f32x4){0.f, 0.f, 0.f, 0.f};
#pragma unroll
        for (int ks = 0; ks < 2; ++ks) {
            const bf16x8 af = *(const bf16x8*)&Qs[wid * 16 + l15][ks * 32 + quad * 8];
#pragma unroll
            for (int nt = 0; nt < 4; ++nt) {
                const bf16x8 bfr = *(const bf16x8*)&Ks[nt * 16 + l15][ks * 32 + quad * 8];
                sacc[nt] = MFMA_B16(af, bfr, sacc[nt]);
            }
        }

        // weights + Z, write Ws (bf16) for A-operand
#pragma unroll
        for (int nt = 0; nt < 4; ++nt) {
#pragma unroll
            for (int r = 0; r < 4; ++r) {
                const int ig = i0 + wid * 16 + quad * 4 + r;
                const int jg = jb + nt * 16 + l15;
                const int dd = jg - ig;
                const bool ok = (jg >= 0) && (jg < S_) && (dd >= -128) && (dd <= 127);
                const float t = __expf(sacc[nt][r] * SCALE - mreg[r]);
                const float wv = ok ? (__expf(t) - 1.0f) : 0.0f;
                const bf16_t wb = (bf16_t)wv;
                zp[r] += (float)wb;  // denominator consistent with bf16 numerator
                Ws[wid * 16 + quad * 4 + r][nt * 16 + l15] = wb;
            }
        }
        __syncthreads();  // Ws visible

        // O += Ws @ Vt
#pragma unroll
        for (int ks = 0; ks < 2; ++ks) {
            const bf16x8 aw = *(const bf16x8*)&Ws[wid * 16 + l15][ks * 32 + quad * 8];
#pragma unroll
            for (int nt = 0; nt < 4; ++nt) {
                const bf16x8 bv = *(const bf16x8*)&Vt[nt * 16 + l15][ks * 32 + quad * 8];
                accO[nt] = MFMA_B16(aw, bv, accO[nt]);
            }
        }
    }

    // Z full reduce across the 16 col-lanes (butterfly leaves sum in all lanes)
    float zfull[4];
#pragma unroll
    for (int r = 0; r < 4; ++r) {
        float z = zp[r];
        z += __shfl_xor(z, 1);
        z += __shfl_xor(z, 2);
        z += __shfl_xor(z, 4);
        z += __shfl_xor(z, 8);
        zfull[r] = z + (float)S_;
    }

#pragma unroll
    for (int nt = 0; nt < 4; ++nt) {
#pragma unroll
        for (int r = 0; r < 4; ++r) {
            const int ig = i0 + wid * 16 + quad * 4 + r;
            const float v = (accO[nt][r] + vsd[nt]) / zfull[r];
            attn[(size_t)(b * S_ + ig) * 1024 + h * 64 + nt * 16 + l15] = (bf16_t)v;
        }
    }
}

// ---------------------------------------------------------------------------
// Launch
// ---------------------------------------------------------------------------
extern "C" void kernel_launch(void* const* d_in, const int* in_sizes, int n_in,
                              void* d_out, int out_size, void* d_ws, size_t ws_size,
                              hipStream_t stream)
{
    const float* x  = (const float*)d_in[0];
    const float* Wq = (const float*)d_in[1];
    const float* Wk = (const float*)d_in[2];
    const float* Wv = (const float*)d_in[3];
    const float* Wo = (const float*)d_in[4];
    float* out = (float*)d_out;

    char* ws = (char*)d_ws;
    // byte offsets
    bf16_t* xb   = (bf16_t*)(ws + 0);          //  8388608 B
    bf16_t* Wqt  = (bf16_t*)(ws + 8388608);    //  2097152 B each
    bf16_t* Wkt  = (bf16_t*)(ws + 10485760);
    bf16_t* Wvt  = (bf16_t*)(ws + 12582912);
    bf16_t* Wot  = (bf16_t*)(ws + 14680064);
    bf16_t* Qh   = (bf16_t*)(ws + 16777216);   //  8388608 B each, [bh][s][64]
    bf16_t* Kh   = (bf16_t*)(ws + 25165824);
    bf16_t* Vh   = (bf16_t*)(ws + 33554432);
    bf16_t* attn = (bf16_t*)(ws + 41943040);   //  8388608 B, [m][1024]
    float*  mrow = (float*)(ws + 50331648);    //   262144 B
    float*  vsp  = (float*)(ws + 50593792);    //    65536 B

    cast_x<<<4096, 256, 0, stream>>>(x, xb);
    tcast_w<<<dim3(32, 32, 4), 256, 0, stream>>>(Wq, Wk, Wv, Wo, Wqt, Wkt, Wvt, Wot);
    gemm_qkv_mfma<<<dim3(8, 32, 3), 256, 0, stream>>>(xb, Wqt, Wkt, Wvt, Qh, Kh, Vh);
    vsum_k<<<32 * 8, 256, 0, stream>>>(Vh, vsp);
    rowmax_mfma<<<dim3(16, 16, 2), 256, 0, stream>>>(Qh, Kh, mrow);
    band_mfma<<<dim3(32, 16, 2), 256, 0, stream>>>(Qh, Kh, Vh, mrow, vsp, attn);
    gemm_out_mfma<<<dim3(8, 32), 256, 0, stream>>>(attn, Wot, out);
}

// Round 4
// 220.855 us; speedup vs baseline: 9.3574x; 1.0404x over previous
//
#include <hip/hip_runtime.h>
#include <math.h>

typedef __bf16 bf16_t;
typedef bf16_t bf16x8 __attribute__((ext_vector_type(8)));
typedef bf16_t bf16x4 __attribute__((ext_vector_type(4)));
typedef float f32x4 __attribute__((ext_vector_type(4)));

constexpr int S_  = 2048;
constexpr float SCALE = 0.125f;  // 1/sqrt(64)

#define MFMA_B16(a, b, c) __builtin_amdgcn_mfma_f32_16x16x32_bf16(a, b, c, 0, 0, 0)

typedef __attribute__((address_space(1))) const void* as1_cvp;
typedef __attribute__((address_space(3))) void* as3_vp;

// async global->LDS, 16B per lane; LDS dest = base + lane*16 (wave-uniform base)
__device__ __forceinline__ void gl2lds16(const void* g, void* l)
{
    __builtin_amdgcn_global_load_lds((as1_cvp)g, (as3_vp)l, 16, 0, 0);
}

// ---------------------------------------------------------------------------
// cast x (f32[4096][1024]) -> bf16
// ---------------------------------------------------------------------------
__global__ __launch_bounds__(256) void cast_x(const float* __restrict__ x,
                                              bf16_t* __restrict__ xb)
{
    const int g = blockIdx.x * 256 + threadIdx.x;
    const float4 v = ((const float4*)x)[g];
    bf16x4 o;
    o[0] = (bf16_t)v.x; o[1] = (bf16_t)v.y; o[2] = (bf16_t)v.z; o[3] = (bf16_t)v.w;
    *(bf16x4*)&xb[(size_t)g * 4] = o;
}

// ---------------------------------------------------------------------------
// transpose-cast weights: Wt[n][k] = (bf16)W[k][n]
// ---------------------------------------------------------------------------
__global__ __launch_bounds__(256) void tcast_w(const float* __restrict__ Wq,
                                               const float* __restrict__ Wk,
                                               const float* __restrict__ Wv,
                                               const float* __restrict__ Wo,
                                               bf16_t* __restrict__ Wqt,
                                               bf16_t* __restrict__ Wkt,
                                               bf16_t* __restrict__ Wvt,
                                               bf16_t* __restrict__ Wot)
{
    const float* src = (blockIdx.z == 0) ? Wq : (blockIdx.z == 1) ? Wk
                      : (blockIdx.z == 2) ? Wv : Wo;
    bf16_t* dst = (blockIdx.z == 0) ? Wqt : (blockIdx.z == 1) ? Wkt
                 : (blockIdx.z == 2) ? Wvt : Wot;
    const int k0 = blockIdx.y * 32, n0 = blockIdx.x * 32;
    __shared__ float T[32][33];
    const int r  = threadIdx.x >> 3;
    const int c4 = (threadIdx.x & 7) * 4;
    const float4 v = *(const float4*)&src[(size_t)(k0 + r) * 1024 + n0 + c4];
    T[r][c4 + 0] = v.x; T[r][c4 + 1] = v.y; T[r][c4 + 2] = v.z; T[r][c4 + 3] = v.w;
    __syncthreads();
    bf16x4 o;
#pragma unroll
    for (int u = 0; u < 4; ++u) o[u] = (bf16_t)T[c4 + u][r];
    *(bf16x4*)&dst[(size_t)(n0 + r) * 1024 + k0 + c4] = o;
}

// ---------------------------------------------------------------------------
// m97-style bf16 MFMA GEMM: C = A[M][1024] @ Bt[N][1024]^T. 128x128 tile,
// BK=32, global_load_lds(16B) staging, unpadded LDS [128][32].
// MFMA called with swapped operands so lane=m, regs=n -> vector stores.
// MODE 0: f32 row-major [.][1024]. MODE 1: bf16 head layout [bh][s][64].
// ---------------------------------------------------------------------------
template <int MODE>
__device__ __forceinline__ void mfma_gemm_body(const bf16_t* __restrict__ A,
                                               const bf16_t* __restrict__ Bt,
                                               void* __restrict__ dst,
                                               int m0, int n0)
{
    __shared__ bf16_t As[4096];  // [128][32]
    __shared__ bf16_t Bs[4096];

    const int tid = threadIdx.x;
    const int lane = tid & 63, wid = tid >> 6;
    const int l15 = lane & 15, quad = lane >> 4;
    const int wm = (wid & 1) * 64, wn = (wid >> 1) * 64;

    // staging: call c in {0,1}: granule = (wid*2+c)*64 + lane
    // row = wid*32 + c*16 + (lane>>2), colgrp8 = (lane&3)*8
    const int srow = wid * 32 + (lane >> 2);
    const int scg8 = (lane & 3) * 8;
    const bf16_t* Ag0 = A  + (size_t)(m0 + srow) * 1024 + scg8;
    const bf16_t* Ag1 = A  + (size_t)(m0 + srow + 16) * 1024 + scg8;
    const bf16_t* Bg0 = Bt + (size_t)(n0 + srow) * 1024 + scg8;
    const bf16_t* Bg1 = Bt + (size_t)(n0 + srow + 16) * 1024 + scg8;
    bf16_t* Al0 = As + (wid * 2 + 0) * 512;
    bf16_t* Al1 = As + (wid * 2 + 1) * 512;
    bf16_t* Bl0 = Bs + (wid * 2 + 0) * 512;
    bf16_t* Bl1 = Bs + (wid * 2 + 1) * 512;

    f32x4 acc[4][4];
#pragma unroll
    for (int i = 0; i < 4; ++i)
#pragma unroll
        for (int j = 0; j < 4; ++j) acc[i][j] = (f32x4){0.f, 0.f, 0.f, 0.f};

    for (int k0 = 0; k0 < 1024; k0 += 32) {
        __syncthreads();  // previous tile's readers done
        gl2lds16(Ag0 + k0, Al0);
        gl2lds16(Ag1 + k0, Al1);
        gl2lds16(Bg0 + k0, Bl0);
        gl2lds16(Bg1 + k0, Bl1);
        __syncthreads();  // drains vmcnt -> LDS data visible

        bf16x8 af[4], bfr[4];
#pragma unroll
        for (int mt = 0; mt < 4; ++mt)
            af[mt] = *(const bf16x8*)&As[(wm + mt * 16 + l15) * 32 + quad * 8];
#pragma unroll
        for (int nt = 0; nt < 4; ++nt)
            bfr[nt] = *(const bf16x8*)&Bs[(wn + nt * 16 + l15) * 32 + quad * 8];
#pragma unroll
        for (int mt = 0; mt < 4; ++mt)
#pragma unroll
            for (int nt = 0; nt < 4; ++nt)
                acc[mt][nt] = MFMA_B16(bfr[nt], af[mt], acc[mt][nt]);  // swapped
    }

    // lane l15 = m-within-tile; quad*4+reg = n-within-tile
#pragma unroll
    for (int mt = 0; mt < 4; ++mt) {
        const int m = m0 + wm + mt * 16 + l15;
#pragma unroll
        for (int nt = 0; nt < 4; ++nt) {
            const int nb = n0 + wn + nt * 16 + quad * 4;
            if (MODE == 0) {
                *(f32x4*)&((float*)dst)[(size_t)m * 1024 + nb] = acc[mt][nt];
            } else {
                const int bb = m >> 11, s = m & 2047;
                const int hh = nb >> 6, d = nb & 63;
                bf16x4 o;
#pragma unroll
                for (int u = 0; u < 4; ++u) o[u] = (bf16_t)acc[mt][nt][u];
                *(bf16x4*)&((bf16_t*)dst)[((size_t)(bb * 16 + hh) * 2048 + s) * 64 + d] = o;
            }
        }
    }
}

__global__ __launch_bounds__(256) void gemm_qkv_mfma(const bf16_t* __restrict__ xb,
                                                     const bf16_t* __restrict__ Wqt,
                                                     const bf16_t* __restrict__ Wkt,
                                                     const bf16_t* __restrict__ Wvt,
                                                     bf16_t* Qh, bf16_t* Kh, bf16_t* Vh)
{
    const bf16_t* Bt = (blockIdx.z == 0) ? Wqt : (blockIdx.z == 1) ? Wkt : Wvt;
    bf16_t* dst = (blockIdx.z == 0) ? Qh : (blockIdx.z == 1) ? Kh : Vh;
    mfma_gemm_body<1>(xb, Bt, dst, blockIdx.y * 128, blockIdx.x * 128);
}

__global__ __launch_bounds__(256) void gemm_out_mfma(const bf16_t* __restrict__ attn,
                                                     const bf16_t* __restrict__ Wot,
                                                     float* __restrict__ out)
{
    mfma_gemm_body<0>(attn, Wot, out, blockIdx.y * 128, blockIdx.x * 128);
}

// ---------------------------------------------------------------------------
// partial V column sums: vsp[bh][seg][d]
// ---------------------------------------------------------------------------
__global__ __launch_bounds__(256) void vsum_k(const bf16_t* __restrict__ Vh,
                                              float* __restrict__ vsp)
{
    const int bh = blockIdx.x >> 3, seg = blockIdx.x & 7;
    const int d = threadIdx.x & 63, jg = threadIdx.x >> 6;
    float s = 0.f;
    const int jb = seg * 256;
    for (int j = jb + jg; j < jb + 256; j += 4)
        s += (float)Vh[(size_t)bh * 131072 + j * 64 + d];
    __shared__ float red[4][64];
    red[jg][d] = s;
    __syncthreads();
    if (jg == 0)
        vsp[(bh * 8 + seg) * 64 + d] = red[0][d] + red[1][d] + red[2][d] + red[3][d];
}

// ---------------------------------------------------------------------------
// rowmax: mrow[bh][i] = SCALE * max_j (q_i . k_j).  grid (16,16,2), 256 thr.
// Block: 128 q-rows; j-chunks of 128. glds staging into [2][128][32] halves.
// Q fragments hoisted (chunk-invariant). Swapped MFMA: lane=i, regs=j.
// ---------------------------------------------------------------------------
__global__ __launch_bounds__(256) void rowmax_mfma(const bf16_t* __restrict__ Qh,
                                                   const bf16_t* __restrict__ Kh,
                                                   float* __restrict__ mrow)
{
    __shared__ bf16_t Qs[8192];  // [2 half][128][32]
    __shared__ bf16_t Ks[8192];

    const int tid = threadIdx.x;
    const int lane = tid & 63, wid = tid >> 6;
    const int l15 = lane & 15, quad = lane >> 4;
    const int bh = blockIdx.z * 16 + blockIdx.y;
    const int i0 = blockIdx.x * 128;
    const bf16_t* Qb = Qh + (size_t)bh * 131072;
    const bf16_t* Kb = Kh + (size_t)bh * 131072;

    // stage Q tile [128][64] -> two [128][32] halves (4 glds calls/wave)
#pragma unroll
    for (int t = 0; t < 4; ++t) {
        const int G = (wid * 4 + t) * 64 + lane;
        const int half = G >> 9, rem = G & 511;
        const int row = rem >> 2, cg8 = (rem & 3) * 8;
        gl2lds16(Qb + (size_t)(i0 + row) * 64 + half * 32 + cg8,
                 Qs + (wid * 4 + t) * 512);
    }
    __syncthreads();

    bf16x8 af[2][2];
#pragma unroll
    for (int mt = 0; mt < 2; ++mt)
#pragma unroll
        for (int ks = 0; ks < 2; ++ks)
            af[mt][ks] = *(const bf16x8*)&Qs[ks * 4096 + (wid * 32 + mt * 16 + l15) * 32 + quad * 8];

    float rmax[2] = {-3.0e38f, -3.0e38f};

    for (int jb = 0; jb < S_; jb += 128) {
        __syncthreads();  // prev chunk readers done
#pragma unroll
        for (int t = 0; t < 4; ++t) {
            const int G = (wid * 4 + t) * 64 + lane;
            const int half = G >> 9, rem = G & 511;
            const int row = rem >> 2, cg8 = (rem & 3) * 8;
            gl2lds16(Kb + (size_t)(jb + row) * 64 + half * 32 + cg8,
                     Ks + (wid * 4 + t) * 512);
        }
        __syncthreads();

#pragma unroll
        for (int nt = 0; nt < 8; ++nt) {
            const bf16x8 b0 = *(const bf16x8*)&Ks[(nt * 16 + l15) * 32 + quad * 8];
            const bf16x8 b1 = *(const bf16x8*)&Ks[4096 + (nt * 16 + l15) * 32 + quad * 8];
#pragma unroll
            for (int mt = 0; mt < 2; ++mt) {
                f32x4 t = (f32x4){0.f, 0.f, 0.f, 0.f};
                t = MFMA_B16(b0, af[mt][0], t);
                t = MFMA_B16(b1, af[mt][1], t);
                rmax[mt] = fmaxf(rmax[mt],
                                 fmaxf(fmaxf(t[0], t[1]), fmaxf(t[2], t[3])));
            }
        }
    }

#pragma unroll
    for (int mt = 0; mt < 2; ++mt) {
        float v = rmax[mt];
        v = fmaxf(v, __shfl_xor(v, 16));
        v = fmaxf(v, __shfl_xor(v, 32));
        if (quad == 0)
            mrow[(size_t)bh * S_ + i0 + wid * 32 + mt * 16 + l15] = v * SCALE;
    }
}

// ---------------------------------------------------------------------------
// band attention via MFMA. grid (32,16,2); block = 64 q-rows of one (b,h).
// Scores MFMA (regs=i), double-exp+mask, Ws->LDS, W@V MFMA swapped (lane=i,
// regs=d) -> bf16x4 attn stores. Z redistributed lane-wise via LDS.
// ---------------------------------------------------------------------------
__global__ __launch_bounds__(256) void band_mfma(const bf16_t* __restrict__ Qh,
                                                 const bf16_t* __restrict__ Kh,
                                                 const bf16_t* __restrict__ Vh,
                                                 const float* __restrict__ mrow,
                                                 const float* __restrict__ vsp,
                                                 bf16_t* __restrict__ attn)
{
    __shared__ bf16_t Qs[64][72];
    __shared__ bf16_t Ks[64][72];
    __shared__ bf16_t Vt[64][72];  // [d][j]
    __shared__ bf16_t Ws[64][72];  // [i][j]
    __shared__ float zsh[4][16];

    const int tid = threadIdx.x;
    const int lane = tid & 63, wid = tid >> 6;
    const int l15 = lane & 15, quad = lane >> 4;
    const int b = blockIdx.z, h = blockIdx.y;
    const int bh = b * 16 + h;
    const int i0 = blockIdx.x * 64;
    const bf16_t* Qb = Qh + (size_t)bh * 131072;
    const bf16_t* Kb = Kh + (size_t)bh * 131072;
    const bf16_t* Vb = Vh + (size_t)bh * 131072;

#pragma unroll
    for (int u = 0; u < 2; ++u) {
        const int c = tid + 256 * u;
        const int row = c >> 3, k8 = (c & 7) * 8;
        *(bf16x8*)&Qs[row][k8] = *(const bf16x8*)&Qb[(size_t)(i0 + row) * 64 + k8];
    }
    __syncthreads();

    bf16x8 aq0 = *(const bf16x8*)&Qs[wid * 16 + l15][quad * 8];
    bf16x8 aq1 = *(const bf16x8*)&Qs[wid * 16 + l15][32 + quad * 8];

    float mreg[4];
#pragma unroll
    for (int r = 0; r < 4; ++r)
        mreg[r] = mrow[(size_t)bh * S_ + i0 + wid * 16 + quad * 4 + r];

    f32x4 vsd4[4];
#pragma unroll
    for (int nt = 0; nt < 4; ++nt) {
        f32x4 s = (f32x4){0.f, 0.f, 0.f, 0.f};
#pragma unroll
        for (int seg = 0; seg < 8; ++seg) {
            const f32x4 p = *(const f32x4*)&vsp[(bh * 8 + seg) * 64 + nt * 16 + quad * 4];
            s[0] += p[0]; s[1] += p[1]; s[2] += p[2]; s[3] += p[3];
        }
        vsd4[nt] = s;
    }

    f32x4 accO[4];
#pragma unroll
    for (int nt = 0; nt < 4; ++nt) accO[nt] = (f32x4){0.f, 0.f, 0.f, 0.f};
    float zp[4] = {0.f, 0.f, 0.f, 0.f};

    const int vjj = tid >> 2;
    const int vd0 = (tid & 3) * 16;

    for (int cb = 0; cb < 5; ++cb) {
        const int jb = i0 - 128 + cb * 64;
        if (jb + 64 <= 0 || jb >= S_) continue;  // block-uniform

        __syncthreads();  // prior chunk's readers done
#pragma unroll
        for (int u = 0; u < 2; ++u) {
            const int c = tid + 256 * u;
            const int row = c >> 3, k8 = (c & 7) * 8;
            const int j = jb + row;
            bf16x8 kv;
            if (j >= 0 && j < S_) kv = *(const bf16x8*)&Kb[(size_t)j * 64 + k8];
            else { bf16_t z = (bf16_t)0.f; kv = (bf16x8){z,z,z,z,z,z,z,z}; }
            *(bf16x8*)&Ks[row][k8] = kv;
        }
        {
            const int j = jb + vjj;
            const bool ok = (j >= 0 && j < S_);
#pragma unroll
            for (int u = 0; u < 2; ++u) {
                bf16x8 vv;
                if (ok) vv = *(const bf16x8*)&Vb[(size_t)j * 64 + vd0 + u * 8];
                else { bf16_t z = (bf16_t)0.f; vv = (bf16x8){z,z,z,z,z,z,z,z}; }
#pragma unroll
                for (int e = 0; e < 8; ++e)
                    Vt[vd0 + u * 8 + e][vjj] = vv[e];
            }
        }
        __syncthreads();

        // scores (regs = i, lane = j)
        f32x4 sacc[4];
#pragma unroll
        for (int nt = 0; nt < 4; ++nt) {
            const bf16x8 b0 = *(const bf16x8*)&Ks[nt * 16 + l15][quad * 8];
            const bf16x8 b1 = *(const bf16x8*)&Ks[nt * 16 + l15][32 + quad * 8];
            f32x4 t = (f32x4){0.f, 0.f, 0.f, 0.f};
            t = MFMA_B16(aq0, b0, t);
            t = MFMA_B16(aq1, b1, t);
            sacc[nt] = t;
        }

        // weights + Z; write Ws
#pragma unroll
        for (int nt = 0; nt < 4; ++nt) {
#pragma unroll
            for (int r = 0; r < 4; ++r) {
                const int ig = i0 + wid * 16 + quad * 4 + r;
                const int jg = jb + nt * 16 + l15;
                const int dd = jg - ig;
                const bool ok = (jg >= 0) && (jg < S_) && (dd >= -128) && (dd <= 127);
                const float t = __expf(sacc[nt][r] * SCALE - mreg[r]);
                const float wv = ok ? (__expf(t) - 1.0f) : 0.0f;
                const bf16_t wb = (bf16_t)wv;
                zp[r] += (float)wb;
                Ws[wid * 16 + quad * 4 + r][nt * 16 + l15] = wb;
            }
        }
        __syncthreads();

        // O += W @ V, swapped: lane = i, regs = d
#pragma unroll
        for (int ks = 0; ks < 2; ++ks) {
            const bf16x8 aw = *(const bf16x8*)&Ws[wid * 16 + l15][ks * 32 + quad * 8];
#pragma unroll
            for (int nt = 0; nt < 4; ++nt) {
                const bf16x8 bv = *(const bf16x8*)&Vt[nt * 16 + l15][ks * 32 + quad * 8];
                accO[nt] = MFMA_B16(bv, aw, accO[nt]);
            }
        }
    }

    // Z: sum over j-lanes; redistribute so lane l15 holds its row's Z
#pragma unroll
    for (int r = 0; r < 4; ++r) {
        float z = zp[r];
        z += __shfl_xor(z, 1);
        z += __shfl_xor(z, 2);
        z += __shfl_xor(z, 4);
        z += __shfl_xor(z, 8);
        if (l15 == 0) zsh[wid][quad * 4 + r] = z + (float)S_;
    }
    __syncthreads();
    const float rz = 1.0f / zsh[wid][l15];

    const int irow = i0 + wid * 16 + l15;
#pragma unroll
    for (int nt = 0; nt < 4; ++nt) {
        bf16x4 o;
#pragma unroll
        for (int r = 0; r < 4; ++r)
            o[r] = (bf16_t)((accO[nt][r] + vsd4[nt][r]) * rz);
        *(bf16x4*)&attn[(size_t)(b * S_ + irow) * 1024 + h * 64 + nt * 16 + quad * 4] = o;
    }
}

// ---------------------------------------------------------------------------
// Launch
// ---------------------------------------------------------------------------
extern "C" void kernel_launch(void* const* d_in, const int* in_sizes, int n_in,
                              void* d_out, int out_size, void* d_ws, size_t ws_size,
                              hipStream_t stream)
{
    const float* x  = (const float*)d_in[0];
    const float* Wq = (const float*)d_in[1];
    const float* Wk = (const float*)d_in[2];
    const float* Wv = (const float*)d_in[3];
    const float* Wo = (const float*)d_in[4];
    float* out = (float*)d_out;

    char* ws = (char*)d_ws;
    bf16_t* xb   = (bf16_t*)(ws + 0);
    bf16_t* Wqt  = (bf16_t*)(ws + 8388608);
    bf16_t* Wkt  = (bf16_t*)(ws + 10485760);
    bf16_t* Wvt  = (bf16_t*)(ws + 12582912);
    bf16_t* Wot  = (bf16_t*)(ws + 14680064);
    bf16_t* Qh   = (bf16_t*)(ws + 16777216);   // [bh][s][64]
    bf16_t* Kh   = (bf16_t*)(ws + 25165824);
    bf16_t* Vh   = (bf16_t*)(ws + 33554432);
    bf16_t* attn = (bf16_t*)(ws + 41943040);   // [m][1024]
    float*  mrow = (float*)(ws + 50331648);
    float*  vsp  = (float*)(ws + 50593792);

    cast_x<<<4096, 256, 0, stream>>>(x, xb);
    tcast_w<<<dim3(32, 32, 4), 256, 0, stream>>>(Wq, Wk, Wv, Wo, Wqt, Wkt, Wvt, Wot);
    gemm_qkv_mfma<<<dim3(8, 32, 3), 256, 0, stream>>>(xb, Wqt, Wkt, Wvt, Qh, Kh, Vh);
    vsum_k<<<32 * 8, 256, 0, stream>>>(Vh, vsp);
    rowmax_mfma<<<dim3(16, 16, 2), 256, 0, stream>>>(Qh, Kh, mrow);
    band_mfma<<<dim3(32, 16, 2), 256, 0, stream>>>(Qh, Kh, Vh, mrow, vsp, attn);
    gemm_out_mfma<<<dim3(8, 32), 256, 0, stream>>>(attn, Wot, out);
}

// Round 5
// 193.303 us; speedup vs baseline: 10.6912x; 1.1425x over previous
//
#include <hip/hip_runtime.h>
#include <math.h>

typedef __bf16 bf16_t;
typedef bf16_t bf16x8 __attribute__((ext_vector_type(8)));
typedef bf16_t bf16x4 __attribute__((ext_vector_type(4)));
typedef float f32x4 __attribute__((ext_vector_type(4)));

constexpr int S_ = 2048;
constexpr float SCALE = 0.125f;  // 1/sqrt(64)

#define MFMA_B16(a, b, c) __builtin_amdgcn_mfma_f32_16x16x32_bf16(a, b, c, 0, 0, 0)

typedef __attribute__((address_space(1))) const void* as1_cvp;
typedef __attribute__((address_space(3))) void* as3_vp;

__device__ __forceinline__ void gl2lds16(const void* g, void* l)
{
    __builtin_amdgcn_global_load_lds((as1_cvp)g, (as3_vp)l, 16, 0, 0);
}

// ---------------------------------------------------------------------------
// prep: cast x -> bf16 (blocks 0..1023), transpose-cast 4 weights (1024..2047),
// zero vsp (block 2048)
// ---------------------------------------------------------------------------
__global__ __launch_bounds__(256) void prep(const float* __restrict__ x,
                                            const float* __restrict__ Wq,
                                            const float* __restrict__ Wk,
                                            const float* __restrict__ Wv,
                                            const float* __restrict__ Wo,
                                            bf16_t* __restrict__ xb,
                                            bf16_t* __restrict__ Wqt,
                                            bf16_t* __restrict__ Wkt,
                                            bf16_t* __restrict__ Wvt,
                                            bf16_t* __restrict__ Wot,
                                            float* __restrict__ vsp)
{
    __shared__ float T[64][65];
    const int blk = blockIdx.x;
    const int tid = threadIdx.x;
    if (blk < 1024) {
        // cast x: 4 float4s per thread
#pragma unroll
        for (int u = 0; u < 4; ++u) {
            const int g = blk * 1024 + u * 256 + tid;
            const float4 v = ((const float4*)x)[g];
            bf16x4 o;
            o[0] = (bf16_t)v.x; o[1] = (bf16_t)v.y;
            o[2] = (bf16_t)v.z; o[3] = (bf16_t)v.w;
            *(bf16x4*)&xb[(size_t)g * 4] = o;
        }
    } else if (blk < 2048) {
        const int rem = blk - 1024;
        const int wsel = rem >> 8, t = rem & 255;
        const float* src = (wsel == 0) ? Wq : (wsel == 1) ? Wk : (wsel == 2) ? Wv : Wo;
        bf16_t* dst = (wsel == 0) ? Wqt : (wsel == 1) ? Wkt : (wsel == 2) ? Wvt : Wot;
        const int k0 = (t >> 4) * 64, n0 = (t & 15) * 64;
        const int rr = tid >> 4, c4 = (tid & 15) * 4;
#pragma unroll
        for (int u = 0; u < 4; ++u) {
            const float4 v = *(const float4*)&src[(size_t)(k0 + u * 16 + rr) * 1024 + n0 + c4];
            T[u * 16 + rr][c4 + 0] = v.x; T[u * 16 + rr][c4 + 1] = v.y;
            T[u * 16 + rr][c4 + 2] = v.z; T[u * 16 + rr][c4 + 3] = v.w;
        }
        __syncthreads();
#pragma unroll
        for (int u = 0; u < 4; ++u) {
            bf16x4 o;
#pragma unroll
            for (int e = 0; e < 4; ++e) o[e] = (bf16_t)T[c4 + e][u * 16 + rr];
            *(bf16x4*)&dst[(size_t)(n0 + u * 16 + rr) * 1024 + k0 + c4] = o;
        }
    } else {
#pragma unroll
        for (int u = 0; u < 8; ++u) vsp[u * 256 + tid] = 0.f;
    }
}

// ---------------------------------------------------------------------------
// m97-style bf16 MFMA GEMM (128x128, BK=32, glds16 staging).
// MFMA swapped (lane=m, regs=n) -> vector stores.
// MODE 0: f32 [m][1024]. MODE 1: bf16 head layout [bh][s][64]; if vsum_out,
// also atomically accumulate column sums (per-head V sums).
// ---------------------------------------------------------------------------
template <int MODE>
__device__ __forceinline__ void mfma_gemm_body(const bf16_t* __restrict__ A,
                                               const bf16_t* __restrict__ Bt,
                                               void* __restrict__ dst,
                                               float* __restrict__ vsum_out,
                                               int m0, int n0)
{
    __shared__ bf16_t As[4096];  // [128][32]
    __shared__ bf16_t Bs[4096];

    const int tid = threadIdx.x;
    const int lane = tid & 63, wid = tid >> 6;
    const int l15 = lane & 15, quad = lane >> 4;
    const int wm = (wid & 1) * 64, wn = (wid >> 1) * 64;

    const int srow = wid * 32 + (lane >> 2);
    const int scg8 = (lane & 3) * 8;
    const bf16_t* Ag0 = A  + (size_t)(m0 + srow) * 1024 + scg8;
    const bf16_t* Ag1 = A  + (size_t)(m0 + srow + 16) * 1024 + scg8;
    const bf16_t* Bg0 = Bt + (size_t)(n0 + srow) * 1024 + scg8;
    const bf16_t* Bg1 = Bt + (size_t)(n0 + srow + 16) * 1024 + scg8;
    bf16_t* Al0 = As + (wid * 2 + 0) * 512;
    bf16_t* Al1 = As + (wid * 2 + 1) * 512;
    bf16_t* Bl0 = Bs + (wid * 2 + 0) * 512;
    bf16_t* Bl1 = Bs + (wid * 2 + 1) * 512;

    f32x4 acc[4][4];
#pragma unroll
    for (int i = 0; i < 4; ++i)
#pragma unroll
        for (int j = 0; j < 4; ++j) acc[i][j] = (f32x4){0.f, 0.f, 0.f, 0.f};

    for (int k0 = 0; k0 < 1024; k0 += 32) {
        __syncthreads();
        gl2lds16(Ag0 + k0, Al0);
        gl2lds16(Ag1 + k0, Al1);
        gl2lds16(Bg0 + k0, Bl0);
        gl2lds16(Bg1 + k0, Bl1);
        __syncthreads();

        bf16x8 af[4], bfr[4];
#pragma unroll
        for (int mt = 0; mt < 4; ++mt)
            af[mt] = *(const bf16x8*)&As[(wm + mt * 16 + l15) * 32 + quad * 8];
#pragma unroll
        for (int nt = 0; nt < 4; ++nt)
            bfr[nt] = *(const bf16x8*)&Bs[(wn + nt * 16 + l15) * 32 + quad * 8];
#pragma unroll
        for (int mt = 0; mt < 4; ++mt)
#pragma unroll
            for (int nt = 0; nt < 4; ++nt)
                acc[mt][nt] = MFMA_B16(bfr[nt], af[mt], acc[mt][nt]);  // lane=m, regs=n
    }

#pragma unroll
    for (int mt = 0; mt < 4; ++mt) {
        const int m = m0 + wm + mt * 16 + l15;
#pragma unroll
        for (int nt = 0; nt < 4; ++nt) {
            const int nb = n0 + wn + nt * 16 + quad * 4;
            if (MODE == 0) {
                *(f32x4*)&((float*)dst)[(size_t)m * 1024 + nb] = acc[mt][nt];
            } else {
                const int bb = m >> 11, s = m & 2047;
                const int hh = nb >> 6, d = nb & 63;
                bf16x4 o;
#pragma unroll
                for (int u = 0; u < 4; ++u) o[u] = (bf16_t)acc[mt][nt][u];
                *(bf16x4*)&((bf16_t*)dst)[((size_t)(bb * 16 + hh) * 2048 + s) * 64 + d] = o;
            }
        }
    }

    // optional per-head column sums (V): sum over m rows, atomically accumulate
    if (MODE == 1 && vsum_out != nullptr) {
        const int bb = m0 >> 11;  // whole 128-row tile in same batch
#pragma unroll
        for (int nt = 0; nt < 4; ++nt) {
            f32x4 p = acc[0][nt];
#pragma unroll
            for (int mt = 1; mt < 4; ++mt) {
                p[0] += acc[mt][nt][0]; p[1] += acc[mt][nt][1];
                p[2] += acc[mt][nt][2]; p[3] += acc[mt][nt][3];
            }
#pragma unroll
            for (int st = 1; st < 16; st <<= 1) {
                p[0] += __shfl_xor(p[0], st);
                p[1] += __shfl_xor(p[1], st);
                p[2] += __shfl_xor(p[2], st);
                p[3] += __shfl_xor(p[3], st);
            }
            if (l15 == 0) {
                const int nI = n0 + wn + nt * 16 + quad * 4;
                float* vp = &vsum_out[(bb * 16 + (nI >> 6)) * 64 + (nI & 63)];
                atomicAdd(vp + 0, p[0]);
                atomicAdd(vp + 1, p[1]);
                atomicAdd(vp + 2, p[2]);
                atomicAdd(vp + 3, p[3]);
            }
        }
    }
}

__global__ __launch_bounds__(256) void gemm_qkv_mfma(const bf16_t* __restrict__ xb,
                                                     const bf16_t* __restrict__ Wqt,
                                                     const bf16_t* __restrict__ Wkt,
                                                     const bf16_t* __restrict__ Wvt,
                                                     bf16_t* Qh, bf16_t* Kh, bf16_t* Vh,
                                                     float* vsp)
{
    const bf16_t* Bt = (blockIdx.z == 0) ? Wqt : (blockIdx.z == 1) ? Wkt : Wvt;
    bf16_t* dst = (blockIdx.z == 0) ? Qh : (blockIdx.z == 1) ? Kh : Vh;
    float* vs = (blockIdx.z == 2) ? vsp : nullptr;
    mfma_gemm_body<1>(xb, Bt, dst, vs, blockIdx.y * 128, blockIdx.x * 128);
}

__global__ __launch_bounds__(256) void gemm_out_mfma(const bf16_t* __restrict__ attn,
                                                     const bf16_t* __restrict__ Wot,
                                                     float* __restrict__ out)
{
    mfma_gemm_body<0>(attn, Wot, out, nullptr, blockIdx.y * 128, blockIdx.x * 128);
}

// ---------------------------------------------------------------------------
// Fused rowmax + band attention. grid (32,16,2); block = 64 q-rows of (b,h).
// Phase 1: full-row max via MFMA scan, 256-j chunks, per-wave j-partition
// (each K fragment feeds 4 MFMAs), Q frags hoisted.
// Phase 2: 5x 64-j band chunks: scores MFMA -> double-exp+mask -> Ws LDS ->
// W@V MFMA (swapped, lane=i, regs=d) -> bf16x4 stores.
// out_i = (sum_band (e^t - 1) v_j + vsum) / (sum_band (e^t - 1) + S)
// ---------------------------------------------------------------------------
__global__ __launch_bounds__(256) void attn_fused(const bf16_t* __restrict__ Qh,
                                                  const bf16_t* __restrict__ Kh,
                                                  const bf16_t* __restrict__ Vh,
                                                  const float* __restrict__ vsp,
                                                  bf16_t* __restrict__ attn)
{
    __shared__ bf16_t Qs[4096];     // [2 half][64][32]
    __shared__ bf16_t Kbig[16384];  // phase1: [2 half][256][32]; phase2 union
    __shared__ float msh[4][4][16]; // [wave][mt][row16] partial maxima
    __shared__ float zsh[4][16];

    bf16_t* Ks2 = Kbig;             // [2][64][32]   (4096 el)
    bf16_t* Vt  = Kbig + 4096;      // [64][72]      (4608 el)  [d][j]
    bf16_t* Wsm = Kbig + 8704;      // [64][72]      (4608 el)  [i][j]

    const int tid = threadIdx.x;
    const int lane = tid & 63, wid = tid >> 6;
    const int l15 = lane & 15, quad = lane >> 4;
    const int b = blockIdx.z, h = blockIdx.y, bh = b * 16 + h;
    const int i0 = blockIdx.x * 64;
    const bf16_t* Qb = Qh + (size_t)bh * 131072;
    const bf16_t* Kb = Kh + (size_t)bh * 131072;
    const bf16_t* Vb = Vh + (size_t)bh * 131072;

    // ---- stage Q [64][64] as [2][64][32] via glds ----
#pragma unroll
    for (int c = 0; c < 2; ++c) {
        const int g = (wid * 2 + c) * 64 + lane;
        const int half = g >> 8, rem = g & 255;
        const int row = rem >> 2, c8 = rem & 3;
        gl2lds16(Qb + (size_t)(i0 + row) * 64 + half * 32 + c8 * 8,
                 Qs + (wid * 2 + c) * 512);
    }
    __syncthreads();

    bf16x8 af[4][2];
#pragma unroll
    for (int mt = 0; mt < 4; ++mt)
#pragma unroll
        for (int ks = 0; ks < 2; ++ks)
            af[mt][ks] = *(const bf16x8*)&Qs[ks * 2048 + (mt * 16 + l15) * 32 + quad * 8];

    // ---- phase 1: rowmax scan, 8 chunks of 256 j ----
    float rmax[4] = {-3.0e38f, -3.0e38f, -3.0e38f, -3.0e38f};

    for (int jc = 0; jc < 8; ++jc) {
        __syncthreads();
#pragma unroll
        for (int c = 0; c < 8; ++c) {
            const int g = (wid * 8 + c) * 64 + lane;
            const int half = g >> 10, rem = g & 1023;
            const int row = rem >> 2, c8 = rem & 3;
            gl2lds16(Kb + (size_t)(jc * 256 + row) * 64 + half * 32 + c8 * 8,
                     Kbig + (size_t)(wid * 8 + c) * 512);
        }
        __syncthreads();
        // wave wid covers j-tiles nt = wid*4 .. wid*4+3
#pragma unroll
        for (int ntl = 0; ntl < 4; ++ntl) {
            const int nt = wid * 4 + ntl;
            const bf16x8 b0 = *(const bf16x8*)&Kbig[(nt * 16 + l15) * 32 + quad * 8];
            const bf16x8 b1 = *(const bf16x8*)&Kbig[8192 + (nt * 16 + l15) * 32 + quad * 8];
#pragma unroll
            for (int mt = 0; mt < 4; ++mt) {
                f32x4 t = (f32x4){0.f, 0.f, 0.f, 0.f};
                t = MFMA_B16(b0, af[mt][0], t);   // lane = i, regs = j
                t = MFMA_B16(b1, af[mt][1], t);
                rmax[mt] = fmaxf(rmax[mt], fmaxf(fmaxf(t[0], t[1]), fmaxf(t[2], t[3])));
            }
        }
    }
#pragma unroll
    for (int mt = 0; mt < 4; ++mt) {
        float v = rmax[mt];
        v = fmaxf(v, __shfl_xor(v, 16));
        v = fmaxf(v, __shfl_xor(v, 32));
        if (quad == 0) msh[wid][mt][l15] = v;
    }
    __syncthreads();  // msh visible; phase-1 Kbig reads complete

    // lane's rows for phase 2 (scores regs): i_local = wid*16 + quad*4 + r
    float mreg[4];
#pragma unroll
    for (int r = 0; r < 4; ++r) {
        const int il = quad * 4 + r;
        mreg[r] = SCALE * fmaxf(fmaxf(msh[0][wid][il], msh[1][wid][il]),
                                fmaxf(msh[2][wid][il], msh[3][wid][il]));
    }

    // phase-2 Q fragment (A-operand rows wid*16..+15) — same layout as af
    const bf16x8 aq0 = *(const bf16x8*)&Qs[(wid * 16 + l15) * 32 + quad * 8];
    const bf16x8 aq1 = *(const bf16x8*)&Qs[2048 + (wid * 16 + l15) * 32 + quad * 8];

    f32x4 vsd4[4];
#pragma unroll
    for (int nt = 0; nt < 4; ++nt)
        vsd4[nt] = *(const f32x4*)&vsp[bh * 64 + nt * 16 + quad * 4];

    f32x4 accO[4];
#pragma unroll
    for (int nt = 0; nt < 4; ++nt) accO[nt] = (f32x4){0.f, 0.f, 0.f, 0.f};
    float zp[4] = {0.f, 0.f, 0.f, 0.f};

    // ---- phase 2: 5 band chunks of 64 j (always fully in-range or skipped) ----
    for (int cb = 0; cb < 5; ++cb) {
        const int jb = i0 - 128 + cb * 64;
        if (jb < 0 || jb >= S_) continue;  // uniform

        __syncthreads();
        // stage K chunk [2][64][32] via glds
#pragma unroll
        for (int c = 0; c < 2; ++c) {
            const int g = (wid * 2 + c) * 64 + lane;
            const int half = g >> 8, rem = g & 255;
            const int row = rem >> 2, c8 = rem & 3;
            gl2lds16(Kb + (size_t)(jb + row) * 64 + half * 32 + c8 * 8,
                     Ks2 + (wid * 2 + c) * 512);
        }
        // stage Vt[d][j]: wave wid owns d = wid*16..+15; thread j = lane
        {
            const bf16x8 v0 = *(const bf16x8*)&Vb[(size_t)(jb + lane) * 64 + wid * 16];
            const bf16x8 v1 = *(const bf16x8*)&Vb[(size_t)(jb + lane) * 64 + wid * 16 + 8];
#pragma unroll
            for (int e = 0; e < 8; ++e) {
                Vt[(wid * 16 + e) * 72 + lane] = v0[e];        // banks (4e+lane/2)%32: 2-way
                Vt[(wid * 16 + 8 + e) * 72 + lane] = v1[e];
            }
        }
        __syncthreads();

        // scores: lane = j, regs = i
        f32x4 sacc[4];
#pragma unroll
        for (int nt = 0; nt < 4; ++nt) {
            const bf16x8 k0 = *(const bf16x8*)&Ks2[(nt * 16 + l15) * 32 + quad * 8];
            const bf16x8 k1 = *(const bf16x8*)&Ks2[2048 + (nt * 16 + l15) * 32 + quad * 8];
            f32x4 t = (f32x4){0.f, 0.f, 0.f, 0.f};
            t = MFMA_B16(aq0, k0, t);
            t = MFMA_B16(aq1, k1, t);
            sacc[nt] = t;
        }

        // weights + Z; write Ws[i][j]
#pragma unroll
        for (int nt = 0; nt < 4; ++nt) {
#pragma unroll
            for (int r = 0; r < 4; ++r) {
                const int ig = i0 + wid * 16 + quad * 4 + r;
                const int jg = jb + nt * 16 + l15;
                const int dd = jg - ig;
                const bool ok = (dd >= -128) && (dd <= 127);
                const float t = __expf(sacc[nt][r] * SCALE - mreg[r]);
                const float wv = ok ? (__expf(t) - 1.0f) : 0.0f;
                const bf16_t wb = (bf16_t)wv;
                zp[r] += (float)wb;
                Wsm[(wid * 16 + quad * 4 + r) * 72 + nt * 16 + l15] = wb;
            }
        }
        __syncthreads();

        // O += W @ V : A = Vt (m=d), B = Ws (n=i) -> lane = i, regs = d
#pragma unroll
        for (int ks = 0; ks < 2; ++ks) {
            const bf16x8 aw = *(const bf16x8*)&Wsm[(wid * 16 + l15) * 72 + ks * 32 + quad * 8];
#pragma unroll
            for (int nt = 0; nt < 4; ++nt) {
                const bf16x8 bv = *(const bf16x8*)&Vt[(nt * 16 + l15) * 72 + ks * 32 + quad * 8];
                accO[nt] = MFMA_B16(bv, aw, accO[nt]);
            }
        }
    }

    // Z: reduce over j-lanes, redistribute so lane l15 holds its row's 1/Z
#pragma unroll
    for (int r = 0; r < 4; ++r) {
        float z = zp[r];
        z += __shfl_xor(z, 1);
        z += __shfl_xor(z, 2);
        z += __shfl_xor(z, 4);
        z += __shfl_xor(z, 8);
        if (l15 == 0) zsh[wid][quad * 4 + r] = z + (float)S_;
    }
    __syncthreads();
    const float rz = 1.0f / zsh[wid][l15];

    const int irow = i0 + wid * 16 + l15;
#pragma unroll
    for (int nt = 0; nt < 4; ++nt) {
        bf16x4 o;
#pragma unroll
        for (int r = 0; r < 4; ++r)
            o[r] = (bf16_t)((accO[nt][r] + vsd4[nt][r]) * rz);
        *(bf16x4*)&attn[(size_t)(b * S_ + irow) * 1024 + h * 64 + nt * 16 + quad * 4] = o;
    }
}

// ---------------------------------------------------------------------------
// Launch: 4 kernels
// ---------------------------------------------------------------------------
extern "C" void kernel_launch(void* const* d_in, const int* in_sizes, int n_in,
                              void* d_out, int out_size, void* d_ws, size_t ws_size,
                              hipStream_t stream)
{
    const float* x  = (const float*)d_in[0];
    const float* Wq = (const float*)d_in[1];
    const float* Wk = (const float*)d_in[2];
    const float* Wv = (const float*)d_in[3];
    const float* Wo = (const float*)d_in[4];
    float* out = (float*)d_out;

    char* ws = (char*)d_ws;
    bf16_t* xb   = (bf16_t*)(ws + 0);
    bf16_t* Wqt  = (bf16_t*)(ws + 8388608);
    bf16_t* Wkt  = (bf16_t*)(ws + 10485760);
    bf16_t* Wvt  = (bf16_t*)(ws + 12582912);
    bf16_t* Wot  = (bf16_t*)(ws + 14680064);
    bf16_t* Qh   = (bf16_t*)(ws + 16777216);   // [bh][s][64]
    bf16_t* Kh   = (bf16_t*)(ws + 25165824);
    bf16_t* Vh   = (bf16_t*)(ws + 33554432);
    bf16_t* attn = (bf16_t*)(ws + 41943040);   // [m][1024]
    float*  vsp  = (float*)(ws + 50331648);    // [bh][64] f32, zeroed by prep

    prep<<<2049, 256, 0, stream>>>(x, Wq, Wk, Wv, Wo, xb, Wqt, Wkt, Wvt, Wot, vsp);
    gemm_qkv_mfma<<<dim3(8, 32, 3), 256, 0, stream>>>(xb, Wqt, Wkt, Wvt, Qh, Kh, Vh, vsp);
    attn_fused<<<dim3(32, 16, 2), 256, 0, stream>>>(Qh, Kh, Vh, vsp, attn);
    gemm_out_mfma<<<dim3(8, 32), 256, 0, stream>>>(attn, Wot, out);
}

// Round 6
// 189.179 us; speedup vs baseline: 10.9243x; 1.0218x over previous
//
#include <hip/hip_runtime.h>
#include <math.h>

typedef __bf16 bf16_t;
typedef bf16_t bf16x8 __attribute__((ext_vector_type(8)));
typedef bf16_t bf16x4 __attribute__((ext_vector_type(4)));
typedef float f32x4 __attribute__((ext_vector_type(4)));

constexpr int S_ = 2048;
constexpr float SCALE = 0.125f;  // 1/sqrt(64)

#define MFMA_B16(a, b, c) __builtin_amdgcn_mfma_f32_16x16x32_bf16(a, b, c, 0, 0, 0)

typedef __attribute__((address_space(1))) const void* as1_cvp;
typedef __attribute__((address_space(3))) void* as3_vp;

__device__ __forceinline__ void gl2lds16(const void* g, void* l)
{
    __builtin_amdgcn_global_load_lds((as1_cvp)g, (as3_vp)l, 16, 0, 0);
}

// ---------------------------------------------------------------------------
// prep: cast x -> bf16 (blocks 0..1023), transpose-cast 4 weights (1024..2047),
// zero vsp (block 2048)
// ---------------------------------------------------------------------------
__global__ __launch_bounds__(256) void prep(const float* __restrict__ x,
                                            const float* __restrict__ Wq,
                                            const float* __restrict__ Wk,
                                            const float* __restrict__ Wv,
                                            const float* __restrict__ Wo,
                                            bf16_t* __restrict__ xb,
                                            bf16_t* __restrict__ Wqt,
                                            bf16_t* __restrict__ Wkt,
                                            bf16_t* __restrict__ Wvt,
                                            bf16_t* __restrict__ Wot,
                                            float* __restrict__ vsp)
{
    __shared__ float T[64][65];
    const int blk = blockIdx.x;
    const int tid = threadIdx.x;
    if (blk < 1024) {
#pragma unroll
        for (int u = 0; u < 4; ++u) {
            const int g = blk * 1024 + u * 256 + tid;
            const float4 v = ((const float4*)x)[g];
            bf16x4 o;
            o[0] = (bf16_t)v.x; o[1] = (bf16_t)v.y;
            o[2] = (bf16_t)v.z; o[3] = (bf16_t)v.w;
            *(bf16x4*)&xb[(size_t)g * 4] = o;
        }
    } else if (blk < 2048) {
        const int rem = blk - 1024;
        const int wsel = rem >> 8, t = rem & 255;
        const float* src = (wsel == 0) ? Wq : (wsel == 1) ? Wk : (wsel == 2) ? Wv : Wo;
        bf16_t* dst = (wsel == 0) ? Wqt : (wsel == 1) ? Wkt : (wsel == 2) ? Wvt : Wot;
        const int k0 = (t >> 4) * 64, n0 = (t & 15) * 64;
        const int rr = tid >> 4, c4 = (tid & 15) * 4;
#pragma unroll
        for (int u = 0; u < 4; ++u) {
            const float4 v = *(const float4*)&src[(size_t)(k0 + u * 16 + rr) * 1024 + n0 + c4];
            T[u * 16 + rr][c4 + 0] = v.x; T[u * 16 + rr][c4 + 1] = v.y;
            T[u * 16 + rr][c4 + 2] = v.z; T[u * 16 + rr][c4 + 3] = v.w;
        }
        __syncthreads();
#pragma unroll
        for (int u = 0; u < 4; ++u) {
            bf16x4 o;
#pragma unroll
            for (int e = 0; e < 4; ++e) o[e] = (bf16_t)T[c4 + e][u * 16 + rr];
            *(bf16x4*)&dst[(size_t)(n0 + u * 16 + rr) * 1024 + k0 + c4] = o;
        }
    } else {
#pragma unroll
        for (int u = 0; u < 8; ++u) vsp[u * 256 + tid] = 0.f;
    }
}

// ---------------------------------------------------------------------------
// m97-style bf16 MFMA GEMM (unchanged from round 5)
// ---------------------------------------------------------------------------
template <int MODE>
__device__ __forceinline__ void mfma_gemm_body(const bf16_t* __restrict__ A,
                                               const bf16_t* __restrict__ Bt,
                                               void* __restrict__ dst,
                                               float* __restrict__ vsum_out,
                                               int m0, int n0)
{
    __shared__ bf16_t As[4096];  // [128][32]
    __shared__ bf16_t Bs[4096];

    const int tid = threadIdx.x;
    const int lane = tid & 63, wid = tid >> 6;
    const int l15 = lane & 15, quad = lane >> 4;
    const int wm = (wid & 1) * 64, wn = (wid >> 1) * 64;

    const int srow = wid * 32 + (lane >> 2);
    const int scg8 = (lane & 3) * 8;
    const bf16_t* Ag0 = A  + (size_t)(m0 + srow) * 1024 + scg8;
    const bf16_t* Ag1 = A  + (size_t)(m0 + srow + 16) * 1024 + scg8;
    const bf16_t* Bg0 = Bt + (size_t)(n0 + srow) * 1024 + scg8;
    const bf16_t* Bg1 = Bt + (size_t)(n0 + srow + 16) * 1024 + scg8;
    bf16_t* Al0 = As + (wid * 2 + 0) * 512;
    bf16_t* Al1 = As + (wid * 2 + 1) * 512;
    bf16_t* Bl0 = Bs + (wid * 2 + 0) * 512;
    bf16_t* Bl1 = Bs + (wid * 2 + 1) * 512;

    f32x4 acc[4][4];
#pragma unroll
    for (int i = 0; i < 4; ++i)
#pragma unroll
        for (int j = 0; j < 4; ++j) acc[i][j] = (f32x4){0.f, 0.f, 0.f, 0.f};

    for (int k0 = 0; k0 < 1024; k0 += 32) {
        __syncthreads();
        gl2lds16(Ag0 + k0, Al0);
        gl2lds16(Ag1 + k0, Al1);
        gl2lds16(Bg0 + k0, Bl0);
        gl2lds16(Bg1 + k0, Bl1);
        __syncthreads();

        bf16x8 af[4], bfr[4];
#pragma unroll
        for (int mt = 0; mt < 4; ++mt)
            af[mt] = *(const bf16x8*)&As[(wm + mt * 16 + l15) * 32 + quad * 8];
#pragma unroll
        for (int nt = 0; nt < 4; ++nt)
            bfr[nt] = *(const bf16x8*)&Bs[(wn + nt * 16 + l15) * 32 + quad * 8];
#pragma unroll
        for (int mt = 0; mt < 4; ++mt)
#pragma unroll
            for (int nt = 0; nt < 4; ++nt)
                acc[mt][nt] = MFMA_B16(bfr[nt], af[mt], acc[mt][nt]);  // lane=m, regs=n
    }

#pragma unroll
    for (int mt = 0; mt < 4; ++mt) {
        const int m = m0 + wm + mt * 16 + l15;
#pragma unroll
        for (int nt = 0; nt < 4; ++nt) {
            const int nb = n0 + wn + nt * 16 + quad * 4;
            if (MODE == 0) {
                *(f32x4*)&((float*)dst)[(size_t)m * 1024 + nb] = acc[mt][nt];
            } else {
                const int bb = m >> 11, s = m & 2047;
                const int hh = nb >> 6, d = nb & 63;
                bf16x4 o;
#pragma unroll
                for (int u = 0; u < 4; ++u) o[u] = (bf16_t)acc[mt][nt][u];
                *(bf16x4*)&((bf16_t*)dst)[((size_t)(bb * 16 + hh) * 2048 + s) * 64 + d] = o;
            }
        }
    }

    if (MODE == 1 && vsum_out != nullptr) {
        const int bb = m0 >> 11;
#pragma unroll
        for (int nt = 0; nt < 4; ++nt) {
            f32x4 p = acc[0][nt];
#pragma unroll
            for (int mt = 1; mt < 4; ++mt) {
                p[0] += acc[mt][nt][0]; p[1] += acc[mt][nt][1];
                p[2] += acc[mt][nt][2]; p[3] += acc[mt][nt][3];
            }
#pragma unroll
            for (int st = 1; st < 16; st <<= 1) {
                p[0] += __shfl_xor(p[0], st);
                p[1] += __shfl_xor(p[1], st);
                p[2] += __shfl_xor(p[2], st);
                p[3] += __shfl_xor(p[3], st);
            }
            if (l15 == 0) {
                const int nI = n0 + wn + nt * 16 + quad * 4;
                float* vp = &vsum_out[(bb * 16 + (nI >> 6)) * 64 + (nI & 63)];
                atomicAdd(vp + 0, p[0]);
                atomicAdd(vp + 1, p[1]);
                atomicAdd(vp + 2, p[2]);
                atomicAdd(vp + 3, p[3]);
            }
        }
    }
}

__global__ __launch_bounds__(256) void gemm_qkv_mfma(const bf16_t* __restrict__ xb,
                                                     const bf16_t* __restrict__ Wqt,
                                                     const bf16_t* __restrict__ Wkt,
                                                     const bf16_t* __restrict__ Wvt,
                                                     bf16_t* Qh, bf16_t* Kh, bf16_t* Vh,
                                                     float* vsp)
{
    const bf16_t* Bt = (blockIdx.z == 0) ? Wqt : (blockIdx.z == 1) ? Wkt : Wvt;
    bf16_t* dst = (blockIdx.z == 0) ? Qh : (blockIdx.z == 1) ? Kh : Vh;
    float* vs = (blockIdx.z == 2) ? vsp : nullptr;
    mfma_gemm_body<1>(xb, Bt, dst, vs, blockIdx.y * 128, blockIdx.x * 128);
}

__global__ __launch_bounds__(256) void gemm_out_mfma(const bf16_t* __restrict__ attn,
                                                     const bf16_t* __restrict__ Wot,
                                                     float* __restrict__ out)
{
    mfma_gemm_body<0>(attn, Wot, out, nullptr, blockIdx.y * 128, blockIdx.x * 128);
}

// ---------------------------------------------------------------------------
// Fused rowmax + band attention, v2.
// 1-D grid of 512 blocks, XCD-swizzled: f -> bh = (f&7) + 8*(seq>>4) so all
// 16 i-tiles of one (b,h) live on one XCD (K/V strip stays L2-resident).
// Block = 128 q-rows. Phase 1: rowmax over 8x256-j chunks, 64 MFMA/wave/chunk,
// Q frags hoisted (dual-use for both phases). Phase 2: 6x64-j band chunks.
// ---------------------------------------------------------------------------
__global__ __launch_bounds__(256, 2) void attn_fused(const bf16_t* __restrict__ Qh,
                                                     const bf16_t* __restrict__ Kh,
                                                     const bf16_t* __restrict__ Vh,
                                                     const float* __restrict__ vsp,
                                                     bf16_t* __restrict__ attn)
{
    __shared__ bf16_t Qs[8192];     // [2 half][128][32]
    __shared__ bf16_t pool[17920];  // p1: Kbig [2][256][32]; p2: Ks2+Vt+Ws
    __shared__ float msh[4][8][16];
    __shared__ float zsh[4][32];

    bf16_t* Ks2 = pool;             // [2][64][32]  (4096)
    bf16_t* Vt  = pool + 4096;      // [64][72]     (4608) [d][j]
    bf16_t* Ws  = pool + 8704;      // [128][72]    (9216) [i][j]

    const int tid = threadIdx.x;
    const int lane = tid & 63, wid = tid >> 6;
    const int l15 = lane & 15, quad = lane >> 4;

    const int f = blockIdx.x;
    const int seq = f >> 3;
    const int bh = (f & 7) + 8 * (seq >> 4);   // XCD-locality: bh % 8 == f % 8
    const int i0 = (seq & 15) * 128;
    const int b = bh >> 4, h = bh & 15;
    const bf16_t* Qb = Qh + (size_t)bh * 131072;
    const bf16_t* Kb = Kh + (size_t)bh * 131072;
    const bf16_t* Vb = Vh + (size_t)bh * 131072;

    // ---- stage Q [128][64] as [2][128][32] (16 granules) ----
#pragma unroll
    for (int c = 0; c < 4; ++c) {
        const int g = wid * 4 + c;
        const int half = g >> 3;
        const int row = (g & 7) * 16 + (lane >> 2);
        gl2lds16(Qb + (size_t)(i0 + row) * 64 + half * 32 + (lane & 3) * 8,
                 Qs + g * 512);
    }
    __syncthreads();

    // Q fragments: dual-use (phase-1 B-operand n=i; phase-2 A-operand m=i)
    bf16x8 af[8][2];
#pragma unroll
    for (int mt = 0; mt < 8; ++mt)
#pragma unroll
        for (int ks = 0; ks < 2; ++ks)
            af[mt][ks] = *(const bf16x8*)&Qs[ks * 4096 + (mt * 16 + l15) * 32 + quad * 8];

    // ---- phase 1: rowmax, 8 chunks of 256 j; waves partition j-tiles ----
    float rmax[8];
#pragma unroll
    for (int mt = 0; mt < 8; ++mt) rmax[mt] = -3.0e38f;

    for (int jc = 0; jc < 8; ++jc) {
        __syncthreads();
#pragma unroll
        for (int c = 0; c < 8; ++c) {
            const int g = wid * 8 + c;
            const int half = g >> 4;
            const int row = (g & 15) * 16 + (lane >> 2);
            gl2lds16(Kb + (size_t)(jc * 256 + row) * 64 + half * 32 + (lane & 3) * 8,
                     pool + g * 512);
        }
        __syncthreads();
#pragma unroll
        for (int ntl = 0; ntl < 4; ++ntl) {
            const int jt = wid * 4 + ntl;
            const bf16x8 b0 = *(const bf16x8*)&pool[(jt * 16 + l15) * 32 + quad * 8];
            const bf16x8 b1 = *(const bf16x8*)&pool[8192 + (jt * 16 + l15) * 32 + quad * 8];
#pragma unroll
            for (int mt = 0; mt < 8; ++mt) {
                f32x4 t = (f32x4){0.f, 0.f, 0.f, 0.f};
                t = MFMA_B16(b0, af[mt][0], t);   // lane = i, regs = j
                t = MFMA_B16(b1, af[mt][1], t);
                rmax[mt] = fmaxf(rmax[mt], fmaxf(fmaxf(t[0], t[1]), fmaxf(t[2], t[3])));
            }
        }
    }
#pragma unroll
    for (int mt = 0; mt < 8; ++mt) {
        float v = rmax[mt];
        v = fmaxf(v, __shfl_xor(v, 16));
        v = fmaxf(v, __shfl_xor(v, 32));
        if (quad == 0) msh[wid][mt][l15] = v;
    }
    __syncthreads();  // msh visible; phase-1 pool reads done

    // phase-2 row maxima: wave owns i-tiles wid*2, wid*2+1; regs index i
    float mreg[2][4];
#pragma unroll
    for (int t = 0; t < 2; ++t)
#pragma unroll
        for (int r = 0; r < 4; ++r) {
            const int mt = wid * 2 + t;
            const int il = quad * 4 + r;
            mreg[t][r] = SCALE * fmaxf(fmaxf(msh[0][mt][il], msh[1][mt][il]),
                                       fmaxf(msh[2][mt][il], msh[3][mt][il]));
        }

    f32x4 vsd4[4];
#pragma unroll
    for (int dt = 0; dt < 4; ++dt)
        vsd4[dt] = *(const f32x4*)&vsp[bh * 64 + dt * 16 + quad * 4];

    f32x4 accO[2][4];
#pragma unroll
    for (int t = 0; t < 2; ++t)
#pragma unroll
        for (int dt = 0; dt < 4; ++dt) accO[t][dt] = (f32x4){0.f, 0.f, 0.f, 0.f};
    float zp[2][4] = {{0.f, 0.f, 0.f, 0.f}, {0.f, 0.f, 0.f, 0.f}};

    // ---- phase 2: 6 band chunks of 64 j ----
    for (int cb = 0; cb < 6; ++cb) {
        const int jb = i0 - 128 + cb * 64;
        if (jb < 0 || jb >= S_) continue;  // block-uniform

        __syncthreads();  // previous chunk's Ks2/Vt/Ws readers done
        // stage K [2][64][32] (8 granules)
#pragma unroll
        for (int c = 0; c < 2; ++c) {
            const int g = wid * 2 + c;
            const int half = g >> 2;
            const int row = (g & 3) * 16 + (lane >> 2);
            gl2lds16(Kb + (size_t)(jb + row) * 64 + half * 32 + (lane & 3) * 8,
                     Ks2 + g * 512);
        }
        // stage Vt[d][j]: wave owns 16 d, lane = j
        {
            const bf16x8 v0 = *(const bf16x8*)&Vb[(size_t)(jb + lane) * 64 + wid * 16];
            const bf16x8 v1 = *(const bf16x8*)&Vb[(size_t)(jb + lane) * 64 + wid * 16 + 8];
#pragma unroll
            for (int e = 0; e < 8; ++e) {
                Vt[(wid * 16 + e) * 72 + lane] = v0[e];
                Vt[(wid * 16 + 8 + e) * 72 + lane] = v1[e];
            }
        }
        __syncthreads();

        // scores + weights for the wave's 2 i-tiles
#pragma unroll
        for (int t = 0; t < 2; ++t) {
            const int mt = wid * 2 + t;
#pragma unroll
            for (int jt4 = 0; jt4 < 4; ++jt4) {
                const bf16x8 k0 = *(const bf16x8*)&Ks2[(jt4 * 16 + l15) * 32 + quad * 8];
                const bf16x8 k1 = *(const bf16x8*)&Ks2[2048 + (jt4 * 16 + l15) * 32 + quad * 8];
                f32x4 sc = (f32x4){0.f, 0.f, 0.f, 0.f};
                sc = MFMA_B16(af[mt][0], k0, sc);   // lane = j, regs = i
                sc = MFMA_B16(af[mt][1], k1, sc);
#pragma unroll
                for (int r = 0; r < 4; ++r) {
                    const int ig = i0 + mt * 16 + quad * 4 + r;
                    const int jg = jb + jt4 * 16 + l15;
                    const int dd = jg - ig;
                    const bool ok = (dd >= -128) && (dd <= 127);
                    const float e1 = __expf(sc[r] * SCALE - mreg[t][r]);
                    const float wv = ok ? (__expf(e1) - 1.0f) : 0.0f;
                    const bf16_t wb = (bf16_t)wv;
                    zp[t][r] += (float)wb;
                    Ws[(mt * 16 + quad * 4 + r) * 72 + jt4 * 16 + l15] = wb;
                }
            }
        }
        __syncthreads();  // Ws visible; Ks2 no longer needed

        // O += W @ V : A = Vt (m=d), B = Ws (n=i) -> lane = i, regs = d
#pragma unroll
        for (int ks = 0; ks < 2; ++ks) {
            bf16x8 bv[4];
#pragma unroll
            for (int dt = 0; dt < 4; ++dt)
                bv[dt] = *(const bf16x8*)&Vt[(dt * 16 + l15) * 72 + ks * 32 + quad * 8];
#pragma unroll
            for (int t = 0; t < 2; ++t) {
                const int mt = wid * 2 + t;
                const bf16x8 aw = *(const bf16x8*)&Ws[(mt * 16 + l15) * 72 + ks * 32 + quad * 8];
#pragma unroll
                for (int dt = 0; dt < 4; ++dt)
                    accO[t][dt] = MFMA_B16(bv[dt], aw, accO[t][dt]);
            }
        }
    }

    // Z: sum over j-lanes; redistribute so lane l15 indexes its row
#pragma unroll
    for (int t = 0; t < 2; ++t)
#pragma unroll
        for (int r = 0; r < 4; ++r) {
            float z = zp[t][r];
            z += __shfl_xor(z, 1);
            z += __shfl_xor(z, 2);
            z += __shfl_xor(z, 4);
            z += __shfl_xor(z, 8);
            if (l15 == 0) zsh[wid][t * 16 + quad * 4 + r] = z + (float)S_;
        }
    __syncthreads();

#pragma unroll
    for (int t = 0; t < 2; ++t) {
        const float rz = 1.0f / zsh[wid][t * 16 + l15];
        const int irow = i0 + (wid * 2 + t) * 16 + l15;
#pragma unroll
        for (int dt = 0; dt < 4; ++dt) {
            bf16x4 o;
#pragma unroll
            for (int r = 0; r < 4; ++r)
                o[r] = (bf16_t)((accO[t][dt][r] + vsd4[dt][r]) * rz);
            *(bf16x4*)&attn[(size_t)(b * S_ + irow) * 1024 + h * 64 + dt * 16 + quad * 4] = o;
        }
    }
}

// ---------------------------------------------------------------------------
// Launch: 4 kernels
// ---------------------------------------------------------------------------
extern "C" void kernel_launch(void* const* d_in, const int* in_sizes, int n_in,
                              void* d_out, int out_size, void* d_ws, size_t ws_size,
                              hipStream_t stream)
{
    const float* x  = (const float*)d_in[0];
    const float* Wq = (const float*)d_in[1];
    const float* Wk = (const float*)d_in[2];
    const float* Wv = (const float*)d_in[3];
    const float* Wo = (const float*)d_in[4];
    float* out = (float*)d_out;

    char* ws = (char*)d_ws;
    bf16_t* xb   = (bf16_t*)(ws + 0);
    bf16_t* Wqt  = (bf16_t*)(ws + 8388608);
    bf16_t* Wkt  = (bf16_t*)(ws + 10485760);
    bf16_t* Wvt  = (bf16_t*)(ws + 12582912);
    bf16_t* Wot  = (bf16_t*)(ws + 14680064);
    bf16_t* Qh   = (bf16_t*)(ws + 16777216);   // [bh][s][64]
    bf16_t* Kh   = (bf16_t*)(ws + 25165824);
    bf16_t* Vh   = (bf16_t*)(ws + 33554432);
    bf16_t* attn = (bf16_t*)(ws + 41943040);   // [m][1024]
    float*  vsp  = (float*)(ws + 50331648);    // [bh][64] f32, zeroed by prep

    prep<<<2049, 256, 0, stream>>>(x, Wq, Wk, Wv, Wo, xb, Wqt, Wkt, Wvt, Wot, vsp);
    gemm_qkv_mfma<<<dim3(8, 32, 3), 256, 0, stream>>>(xb, Wqt, Wkt, Wvt, Qh, Kh, Vh, vsp);
    attn_fused<<<512, 256, 0, stream>>>(Qh, Kh, Vh, vsp, attn);
    gemm_out_mfma<<<dim3(8, 32), 256, 0, stream>>>(attn, Wot, out);
}